// Round 2
// baseline (17541.576 us; speedup 1.0000x reference)
//
#include <hip/hip_runtime.h>
#include <math.h>

// ---------- types / helpers ----------
using bf16x8 = __attribute__((ext_vector_type(8))) short;
using f32x4  = __attribute__((ext_vector_type(4))) float;
typedef unsigned short u16;
typedef unsigned int   u32;

#define EPSBN 1e-3f

__device__ __forceinline__ u16 f2bf(float f){
  union { float f; u32 u; } c; c.f = f;
  u32 u = c.u + 0x7fffu + ((c.u >> 16) & 1u);
  return (u16)(u >> 16);
}
__device__ __forceinline__ float bf2f(u16 b){
  union { u32 u; float f; } c; c.u = ((u32)b) << 16; return c.f;
}
__device__ __forceinline__ void splitstore(float v, u16* ph, u16* pl){
  u16 h = f2bf(v); *ph = h; *pl = f2bf(v - bf2f(h));
}
__device__ __forceinline__ f32x4 MFMA(bf16x8 a, bf16x8 b, f32x4 c){
  return __builtin_amdgcn_mfma_f32_16x16x32_bf16(a, b, c, 0, 0, 0);
}

// ---------- prep kernels (BN folding, transpose, bf16 hi/lo split) ----------
__global__ __launch_bounds__(256) void k_bn1_split(
    const float* __restrict__ x, const float* __restrict__ g, const float* __restrict__ b,
    const float* __restrict__ m, const float* __restrict__ v,
    u16* __restrict__ oh, u16* __restrict__ ol)
{
  int i = blockIdx.x*256 + threadIdx.x;
  if (i >= 2048000) return;
  int ci = i % 80;
  float s = g[ci] * rsqrtf(v[ci] + EPSBN);
  float val = (x[i] - m[ci]) * s + b[ci];
  splitstore(val, oh+i, ol+i);
}

// conv1 weights -> [co][kf], kf = kw*80+ci, padded K 400->416 with zeros
__global__ __launch_bounds__(256) void k_prep_c1w(
    const float* __restrict__ w0, u16* __restrict__ oh, u16* __restrict__ ol)
{
  int i = blockIdx.x*256 + threadIdx.x;
  if (i >= 512*416) return;
  int co = i / 416, kf = i - co*416;
  float val = 0.f;
  if (kf < 400){ int kw = kf/80, ci = kf - kw*80; val = w0[(kw*80+ci)*512 + co]; }
  splitstore(val, oh+i, ol+i);
}

// conv2 weights -> [co][kf], kf = kw*512+ci  (K=2560)
__global__ __launch_bounds__(256) void k_prep_c2w(
    const float* __restrict__ w1, u16* __restrict__ oh, u16* __restrict__ ol)
{
  int i = blockIdx.x*256 + threadIdx.x;
  if (i >= 5*512*512) return;
  int co = i & 511, ci = (i >> 9) & 511, kw = i >> 18;
  long o = (long)co*2560 + kw*512 + ci;
  splitstore(w1[i], oh+o, ol+o);
}

// gru Wx -> [l*2+d][n][k], BN2 scale folded into layer-0 rows
__global__ __launch_bounds__(256) void k_prep_wx(
    const float* __restrict__ wx, const float* __restrict__ g2, const float* __restrict__ v2,
    u16* __restrict__ oh, u16* __restrict__ ol)
{
  long i = (long)blockIdx.x*256 + threadIdx.x;
  if (i >= 6L*512*1536) return;
  int n = (int)(i % 1536); long r2 = i / 1536; int k = (int)(r2 % 512); int ld = (int)(r2 / 512);
  float s = (ld < 2) ? g2[k]*rsqrtf(v2[k]+EPSBN) : 1.f;
  long o = ((long)ld*1536 + n)*512 + k;
  splitstore(wx[i]*s, oh+o, ol+o);
}

__global__ __launch_bounds__(256) void k_prep_wh(
    const float* __restrict__ wh, u16* __restrict__ oh, u16* __restrict__ ol)
{
  long i = (long)blockIdx.x*256 + threadIdx.x;
  if (i >= 6L*512*1536) return;
  int n = (int)(i % 1536); long r2 = i / 1536; int k = (int)(r2 % 512); int ld = (int)(r2 / 512);
  long o = ((long)ld*1536 + n)*512 + k;
  splitstore(wh[i], oh+o, ol+o);
}

// gru biases: xbias[ld][n] = input bias (+ t2 @ Wx for layer 0), hbias = recurrent bias
__global__ __launch_bounds__(256) void k_prep_grub(
    const float* __restrict__ gb, const float* __restrict__ wx,
    const float* __restrict__ g2, const float* __restrict__ b2,
    const float* __restrict__ m2, const float* __restrict__ v2,
    float* __restrict__ xbias, float* __restrict__ hbias)
{
  int i = blockIdx.x*256 + threadIdx.x;
  if (i >= 6*1536) return;
  int n = i % 1536, ld = i / 1536;
  float xv = gb[(ld*2 + 0)*1536 + n];
  float hv = gb[(ld*2 + 1)*1536 + n];
  if (ld < 2){
    float acc = 0.f;
    for (int k = 0; k < 512; ++k){
      float s = g2[k]*rsqrtf(v2[k]+EPSBN);
      float t = b2[k] - m2[k]*s;
      acc += t * wx[((long)ld*512 + k)*1536 + n];
    }
    xv += acc;
  }
  xbias[i] = xv; hbias[i] = hv;
}

// fc weights with BN3 fold -> [n][k]
__global__ __launch_bounds__(256) void k_prep_fcw(
    const float* __restrict__ fw, const float* __restrict__ g3, const float* __restrict__ v3,
    u16* __restrict__ oh, u16* __restrict__ ol)
{
  int i = blockIdx.x*256 + threadIdx.x;
  if (i >= 512*512) return;
  int n = i & 511, k = i >> 9;
  float s = g3[k]*rsqrtf(v3[k]+EPSBN);
  long o = (long)n*512 + k;
  splitstore(fw[i]*s, oh+o, ol+o);
}

__global__ __launch_bounds__(256) void k_prep_fcb(
    const float* __restrict__ fw, const float* __restrict__ fb,
    const float* __restrict__ g3, const float* __restrict__ b3,
    const float* __restrict__ m3, const float* __restrict__ v3,
    float* __restrict__ ob)
{
  int n = blockIdx.x*256 + threadIdx.x;
  if (n >= 512) return;
  float acc = fb[n];
  for (int k = 0; k < 512; ++k){
    float s = g3[k]*rsqrtf(v3[k]+EPSBN);
    float t = b3[k] - m3[k]*s;
    acc += t * fw[k*512 + n];
  }
  ob[n] = acc;
}

__global__ __launch_bounds__(256) void k_prep_smw(
    const float* __restrict__ sw, u16* __restrict__ oh, u16* __restrict__ ol)
{
  long i = (long)blockIdx.x*256 + threadIdx.x;
  if (i >= 512L*6000) return;
  int n = (int)(i % 6000); int k = (int)(i / 6000);
  long o = (long)n*512 + k;
  splitstore(sw[i], oh+o, ol+o);
}

__global__ __launch_bounds__(256) void k_sumsplit(
    const float* __restrict__ a, const float* __restrict__ b,
    u16* __restrict__ oh, u16* __restrict__ ol)
{
  int i = blockIdx.x*256 + threadIdx.x;
  if (i >= 6352*512) return;
  splitstore(a[i] + b[i], oh+i, ol+i);
}

// ---------- split-bf16 GEMM: C[M,N] = A[M,K(hi/lo)] @ Bt[N,K(hi/lo)] + bias ----------
// AMODE 0: direct A[m][k].  AMODE 1: conv gather CW=80.  AMODE 2: conv gather CW=512.
// EPI 0: f32 out. EPI 1: relu -> split out. EPI 2: clip(0,20) -> split out.
template<int AMODE, int EPI>
__global__ __launch_bounds__(256,1)
void gemm_split(const u16* __restrict__ Ah, const u16* __restrict__ Al,
                const u16* __restrict__ Bh, const u16* __restrict__ Bl,
                const float* __restrict__ bias,
                float* __restrict__ outF, u16* __restrict__ outH, u16* __restrict__ outL,
                int M, int N, int K, int Kvalid, int TIN, int TOUT)
{
  constexpr int CW = (AMODE==1) ? 80 : 512;
  const int tid  = threadIdx.x;
  const int lane = tid & 63;
  const int w    = tid >> 6;
  const int wm = w >> 1, wn = w & 1;
  const int r  = lane & 15, kg = lane >> 4;
  const int m0 = blockIdx.y * 64 + wm * 32;
  const int n0 = blockIdx.x * 64 + wn * 32;

  long abase[2];
  #pragma unroll
  for (int mt = 0; mt < 2; ++mt){
    int m = m0 + mt*16 + r;
    int mc = m < M ? m : M - 1;
    if (AMODE == 0) abase[mt] = (long)mc * K;
    else { int bb = mc / TOUT; int tt = mc - bb * TOUT; abase[mt] = ((long)bb * TIN + 2*tt) * CW; }
  }
  long bbase[2];
  #pragma unroll
  for (int nt = 0; nt < 2; ++nt){
    int n = n0 + nt*16 + r;
    int nc = n < N ? n : N - 1;
    bbase[nt] = (long)nc * K;
  }

  f32x4 acc[2][2];
  #pragma unroll
  for (int a_ = 0; a_ < 2; ++a_)
    #pragma unroll
    for (int b_ = 0; b_ < 2; ++b_) acc[a_][b_] = f32x4{0.f,0.f,0.f,0.f};

  const bf16x8 zfrag = {0,0,0,0,0,0,0,0};
  const int koff = kg * 8;
  const int KT = K >> 5;
  for (int kt = 0; kt < KT; ++kt){
    int kf = kt*32 + koff;
    bf16x8 ah[2], al[2], bh[2], bl[2];
    #pragma unroll
    for (int nt = 0; nt < 2; ++nt){
      bh[nt] = *(const bf16x8*)(Bh + bbase[nt] + kf);
      bl[nt] = *(const bf16x8*)(Bl + bbase[nt] + kf);
    }
    #pragma unroll
    for (int mt = 0; mt < 2; ++mt){
      if (AMODE == 0){
        long ao = abase[mt] + kf;
        ah[mt] = *(const bf16x8*)(Ah + ao); al[mt] = *(const bf16x8*)(Al + ao);
      } else {
        if (kf < Kvalid){
          int kw = kf / CW; int ci = kf - kw*CW;
          long ao = abase[mt] + (long)kw*CW + ci;
          ah[mt] = *(const bf16x8*)(Ah + ao); al[mt] = *(const bf16x8*)(Al + ao);
        } else { ah[mt] = zfrag; al[mt] = zfrag; }
      }
    }
    #pragma unroll
    for (int mt = 0; mt < 2; ++mt)
      #pragma unroll
      for (int nt = 0; nt < 2; ++nt){
        acc[mt][nt] = MFMA(ah[mt], bh[nt], acc[mt][nt]);
        acc[mt][nt] = MFMA(ah[mt], bl[nt], acc[mt][nt]);
        acc[mt][nt] = MFMA(al[mt], bh[nt], acc[mt][nt]);
      }
  }

  #pragma unroll
  for (int nt = 0; nt < 2; ++nt){
    int n = n0 + nt*16 + r;
    if (n >= N) continue;
    float bv = bias ? bias[n] : 0.f;
    #pragma unroll
    for (int mt = 0; mt < 2; ++mt){
      #pragma unroll
      for (int q = 0; q < 4; ++q){
        int m = m0 + mt*16 + kg*4 + q;
        if (m >= M) continue;
        float v = acc[mt][nt][q] + bv;
        if (EPI == 1) v = fmaxf(v, 0.f);
        if (EPI == 2) v = fminf(fmaxf(v, 0.f), 20.f);
        long o = (long)m * N + n;
        if (EPI == 0) outF[o] = v;
        else { u16 h = f2bf(v); outH[o] = h; outL[o] = f2bf(v - bf2f(h)); }
      }
    }
  }
}

// ---------- persistent bidirectional GRU layer ----------
// 64 blocks: dir = bx>>5, slice s = bx&31 (16 h-cols each). Wh fragments held in VGPRs.
// Per-step sync: per-direction monotonic counter barrier + threadfence.
__global__ __launch_bounds__(256,1)
void gru_layer(const float* __restrict__ xp,     // [2][6352][1536]
               const u16* __restrict__ WhH, const u16* __restrict__ WhL, // [2][1536][512]
               const float* __restrict__ hbias,  // [2][1536]
               float* __restrict__ yf, float* __restrict__ yb, // [6352][512] each
               u16* __restrict__ hbH_, u16* __restrict__ hbL_, // [2][2][16][512] each plane
               u32* __restrict__ counters)       // [2]
{
  const int dir = blockIdx.x >> 5;
  const int s   = blockIdx.x & 31;
  const int tid = threadIdx.x, lane = tid & 63, w = tid >> 6;
  const int r = lane & 15, kg = lane >> 4;

  const float* xpd = xp + (long)dir * (6352L*1536);
  const u16* whh = WhH + (long)dir * (1536L*512);
  const u16* whl = WhL + (long)dir * (1536L*512);
  const float* hb = hbias + dir * 1536;
  float* y = dir ? yb : yf;
  u16* hbH = hbH_ + dir * (2*8192);
  u16* hbL = hbL_ + dir * (2*8192);
  u32* cnt = counters + dir;

  __shared__ float red[4][3][64][4];

  // persistent Wh fragments: wave w covers ktiles 4w..4w+3; gates g=0..2
  bf16x8 Bh[3][4], Bl[3][4];
  #pragma unroll
  for (int g = 0; g < 3; ++g){
    long nb = (long)(g*512 + s*16 + r) * 512;
    #pragma unroll
    for (int kk = 0; kk < 4; ++kk){
      int k = (w*4 + kk)*32 + kg*8;
      Bh[g][kk] = *(const bf16x8*)(whh + nb + k);
      Bl[g][kk] = *(const bf16x8*)(whl + nb + k);
    }
  }

  const int gb = tid >> 4, gj = tid & 15;
  const int gcol = s*16 + gj;
  const float bz = hb[gcol], br = hb[512 + gcol], bhh = hb[1024 + gcol];
  const int rl = ((gb >> 2) << 4) | gj;  // lane holding our (row=gb,col=gj)
  const int rq = gb & 3;
  float hreg = 0.f;

  for (int t = 0; t < 397; ++t){
    const int tpos = dir ? (396 - t) : t;
    const long xb_ = ((long)gb*397 + tpos)*1536 + gcol;
    float xz = xpd[xb_], xr = xpd[xb_ + 512], xh = xpd[xb_ + 1024];

    f32x4 a0 = f32x4{0.f,0.f,0.f,0.f}, a1 = a0, a2 = a0;
    if (t > 0){
      if (tid == 0){
        u32 tgt = 32u * (u32)t;
        while (__hip_atomic_load(cnt, __ATOMIC_RELAXED, __HIP_MEMORY_SCOPE_AGENT) < tgt)
          __builtin_amdgcn_s_sleep(1);
      }
      __syncthreads();
      __threadfence();  // acquire: see peers' h stores
      const u16* hH = hbH + (t & 1) * 8192;
      const u16* hL = hbL + (t & 1) * 8192;
      const int rb = r * 512 + kg * 8;
      #pragma unroll
      for (int kk = 0; kk < 4; ++kk){
        int k = (w*4 + kk) * 32;
        bf16x8 ah = *(const bf16x8*)(hH + rb + k);
        bf16x8 al = *(const bf16x8*)(hL + rb + k);
        a0 = MFMA(ah, Bh[0][kk], a0); a0 = MFMA(ah, Bl[0][kk], a0); a0 = MFMA(al, Bh[0][kk], a0);
        a1 = MFMA(ah, Bh[1][kk], a1); a1 = MFMA(ah, Bl[1][kk], a1); a1 = MFMA(al, Bh[1][kk], a1);
        a2 = MFMA(ah, Bh[2][kk], a2); a2 = MFMA(ah, Bl[2][kk], a2); a2 = MFMA(al, Bh[2][kk], a2);
      }
    }
    *(f32x4*)&red[w][0][lane][0] = a0;
    *(f32x4*)&red[w][1][lane][0] = a1;
    *(f32x4*)&red[w][2][lane][0] = a2;
    __syncthreads();
    float rz = bz, rr = br, rh = bhh;
    #pragma unroll
    for (int ww = 0; ww < 4; ++ww){
      rz += red[ww][0][rl][rq];
      rr += red[ww][1][rl][rq];
      rh += red[ww][2][rl][rq];
    }
    float z  = 1.f / (1.f + expf(-(xz + rz)));
    float rg = 1.f / (1.f + expf(-(xr + rr)));
    float hh = fmaxf(xh + rg * rh, 0.f);
    hreg = z * hreg + (1.f - z) * hh;

    y[((long)gb*397 + tpos)*512 + gcol] = hreg;
    {
      u16* oH = hbH + ((t+1) & 1) * 8192;
      u16* oL = hbL + ((t+1) & 1) * 8192;
      u16 h = f2bf(hreg);
      oH[gb*512 + gcol] = h;
      oL[gb*512 + gcol] = f2bf(hreg - bf2f(h));
    }
    __threadfence();   // release our h stores
    __syncthreads();
    if (tid == 0)
      __hip_atomic_fetch_add(cnt, 1u, __ATOMIC_RELAXED, __HIP_MEMORY_SCOPE_AGENT);
  }
}

// ---------- in-place row softmax on d_out [6352][6000] ----------
__global__ __launch_bounds__(256,1) void k_softmax(float* __restrict__ out)
{
  const int tid = threadIdx.x;
  float* prow = out + (long)blockIdx.x * 6000;
  float vals[24];
  float mx = -3.0e38f;
  #pragma unroll
  for (int i = 0; i < 24; ++i){
    int idx = tid + i*256;
    vals[i] = (idx < 6000) ? prow[idx] : -3.0e38f;
    mx = fmaxf(mx, vals[i]);
  }
  #pragma unroll
  for (int o = 32; o; o >>= 1) mx = fmaxf(mx, __shfl_xor(mx, o));
  __shared__ float sred[4];
  if ((tid & 63) == 0) sred[tid >> 6] = mx;
  __syncthreads();
  mx = fmaxf(fmaxf(sred[0], sred[1]), fmaxf(sred[2], sred[3]));
  __syncthreads();
  float sum = 0.f;
  #pragma unroll
  for (int i = 0; i < 24; ++i){
    int idx = tid + i*256;
    vals[i] = (idx < 6000) ? expf(vals[i] - mx) : 0.f;
    sum += vals[i];
  }
  #pragma unroll
  for (int o = 32; o; o >>= 1) sum += __shfl_xor(sum, o);
  if ((tid & 63) == 0) sred[tid >> 6] = sum;
  __syncthreads();
  sum = sred[0] + sred[1] + sred[2] + sred[3];
  float inv = 1.f / sum;
  #pragma unroll
  for (int i = 0; i < 24; ++i){
    int idx = tid + i*256;
    if (idx < 6000) prow[idx] = vals[i] * inv;
  }
}

// ---------- host ----------
extern "C" void kernel_launch(void* const* d_in, const int* in_sizes, int n_in,
                              void* d_out, int out_size, void* d_ws, size_t ws_size,
                              hipStream_t stream)
{
  (void)in_sizes; (void)n_in; (void)out_size; (void)ws_size;
  const float* x    = (const float*)d_in[0];
  const float* bn1g = (const float*)d_in[1];
  const float* bn1b = (const float*)d_in[2];
  const float* bn1m = (const float*)d_in[3];
  const float* bn1v = (const float*)d_in[4];
  const float* cw0  = (const float*)d_in[5];
  const float* cb0  = (const float*)d_in[6];
  const float* cw1  = (const float*)d_in[7];
  const float* cb1  = (const float*)d_in[8];
  const float* bn2g = (const float*)d_in[9];
  const float* bn2b = (const float*)d_in[10];
  const float* bn2m = (const float*)d_in[11];
  const float* bn2v = (const float*)d_in[12];
  const float* gwx  = (const float*)d_in[13];
  const float* gwh  = (const float*)d_in[14];
  const float* gbia = (const float*)d_in[15];
  const float* bn3g = (const float*)d_in[16];
  const float* bn3b = (const float*)d_in[17];
  const float* bn3m = (const float*)d_in[18];
  const float* bn3v = (const float*)d_in[19];
  const float* fcw  = (const float*)d_in[20];
  const float* fcb  = (const float*)d_in[21];
  const float* smw  = (const float*)d_in[22];
  const float* smb  = (const float*)d_in[23];

  char* p = (char*)d_ws;
  auto alloc = [&](size_t bytes)->char*{
    char* q = p; p += (bytes + 255) & ~(size_t)255; return q;
  };
  const size_t NX=2048000, NC1W=512*416, NC1O=12768L*512, NC2W=512*2560,
               NC2O=6352L*512, NWX=6L*1536*512, NXP=2L*6352*1536,
               NSMW=6000L*512, NFCW=512*512, NHB=2L*2*8192;

  u16 *xbnH=(u16*)alloc(NX*2),  *xbnL=(u16*)alloc(NX*2);
  u16 *c1wH=(u16*)alloc(NC1W*2),*c1wL=(u16*)alloc(NC1W*2);
  u16 *c1oH=(u16*)alloc(NC1O*2),*c1oL=(u16*)alloc(NC1O*2);
  u16 *c2wH=(u16*)alloc(NC2W*2),*c2wL=(u16*)alloc(NC2W*2);
  u16 *c2oH=(u16*)alloc(NC2O*2),*c2oL=(u16*)alloc(NC2O*2);
  u16 *wxH=(u16*)alloc(NWX*2),  *wxL=(u16*)alloc(NWX*2);
  u16 *whH=(u16*)alloc(NWX*2),  *whL=(u16*)alloc(NWX*2);
  float *xbias=(float*)alloc(6*1536*4), *hbias=(float*)alloc(6*1536*4);
  float *xp=(float*)alloc(NXP*4);
  float *yf=(float*)alloc(NC2O*4), *yb=(float*)alloc(NC2O*4);
  u16 *ysH=(u16*)alloc(NC2O*2), *ysL=(u16*)alloc(NC2O*2);
  u16 *fcwH=(u16*)alloc(NFCW*2),*fcwL=(u16*)alloc(NFCW*2);
  float *fcb2=(float*)alloc(512*4);
  u16 *fcoH=(u16*)alloc(NC2O*2),*fcoL=(u16*)alloc(NC2O*2);
  u16 *smwH=(u16*)alloc(NSMW*2),*smwL=(u16*)alloc(NSMW*2);
  u16 *hbH=(u16*)alloc(NHB*2),  *hbL=(u16*)alloc(NHB*2);
  u32 *counters=(u32*)alloc(64);

  hipMemsetAsync(counters, 0, 64, stream);

  k_bn1_split<<<8000,256,0,stream>>>(x, bn1g,bn1b,bn1m,bn1v, xbnH,xbnL);
  k_prep_c1w <<<832,256,0,stream>>>(cw0, c1wH,c1wL);
  k_prep_c2w <<<5120,256,0,stream>>>(cw1, c2wH,c2wL);
  k_prep_wx  <<<18432,256,0,stream>>>(gwx, bn2g,bn2v, wxH,wxL);
  k_prep_wh  <<<18432,256,0,stream>>>(gwh, whH,whL);
  k_prep_grub<<<36,256,0,stream>>>(gbia, gwx, bn2g,bn2b,bn2m,bn2v, xbias,hbias);
  k_prep_fcw <<<1024,256,0,stream>>>(fcw, bn3g,bn3v, fcwH,fcwL);
  k_prep_fcb <<<2,256,0,stream>>>(fcw,fcb, bn3g,bn3b,bn3m,bn3v, fcb2);
  k_prep_smw <<<12000,256,0,stream>>>(smw, smwH,smwL);

  // conv1: M=12768, N=512, K=416 (valid 400), stride2 gather from xbn [16*1600][80]
  gemm_split<1,1><<<dim3(8,200),256,0,stream>>>(xbnH,xbnL, c1wH,c1wL, cb0,
      nullptr, c1oH,c1oL, 12768,512,416, 400, 1600,798);
  // conv2: M=6352, N=512, K=2560, gather from c1o [12768][512]
  gemm_split<2,1><<<dim3(8,100),256,0,stream>>>(c1oH,c1oL, c2wH,c2wL, cb1,
      nullptr, c2oH,c2oL, 6352,512,2560, 2560, 798,397);

  const u16 *aH = c2oH, *aL = c2oL;
  for (int l = 0; l < 3; ++l){
    for (int d = 0; d < 2; ++d){
      gemm_split<0,0><<<dim3(24,100),256,0,stream>>>(aH,aL,
          wxH + (size_t)(l*2+d)*786432, wxL + (size_t)(l*2+d)*786432,
          xbias + (l*2+d)*1536,
          xp + (size_t)d*9756672, nullptr,nullptr,
          6352,1536,512, 512, 0,0);
    }
    gru_layer<<<64,256,0,stream>>>(xp,
        whH + (size_t)l*2*786432, whL + (size_t)l*2*786432,
        hbias + l*2*1536, yf,yb, hbH,hbL, counters + l*2);
    k_sumsplit<<<12704,256,0,stream>>>(yf,yb, ysH,ysL);
    aH = ysH; aL = ysL;
  }

  // fc: clip(relu(x@W+b),20) -> split
  gemm_split<0,2><<<dim3(8,100),256,0,stream>>>(ysH,ysL, fcwH,fcwL, fcb2,
      nullptr, fcoH,fcoL, 6352,512,512, 512, 0,0);
  // logits -> d_out (f32), then in-place softmax
  gemm_split<0,0><<<dim3(94,100),256,0,stream>>>(fcoH,fcoL, smwH,smwL, smb,
      (float*)d_out, nullptr,nullptr, 6352,6000,512, 512, 0,0);
  k_softmax<<<6352,256,0,stream>>>((float*)d_out);
}

// Round 3
// 17464.998 us; speedup vs baseline: 1.0044x; 1.0044x over previous
//
#include <hip/hip_runtime.h>
#include <math.h>

// ---------- types / helpers ----------
using bf16x8 = __attribute__((ext_vector_type(8))) short;
using f32x4  = __attribute__((ext_vector_type(4))) float;
typedef unsigned short u16;
typedef unsigned int   u32;

#define EPSBN 1e-3f

__device__ __forceinline__ u16 f2bf(float f){
  union { float f; u32 u; } c; c.f = f;
  u32 u = c.u + 0x7fffu + ((c.u >> 16) & 1u);
  return (u16)(u >> 16);
}
__device__ __forceinline__ float bf2f(u16 b){
  union { u32 u; float f; } c; c.u = ((u32)b) << 16; return c.f;
}
__device__ __forceinline__ void splitstore(float v, u16* ph, u16* pl){
  u16 h = f2bf(v); *ph = h; *pl = f2bf(v - bf2f(h));
}
__device__ __forceinline__ f32x4 MFMA(bf16x8 a, bf16x8 b, f32x4 c){
  return __builtin_amdgcn_mfma_f32_16x16x32_bf16(a, b, c, 0, 0, 0);
}

// ---------- prep kernels (BN folding, transpose, bf16 hi/lo split) ----------
__global__ __launch_bounds__(256) void k_bn1_split(
    const float* __restrict__ x, const float* __restrict__ g, const float* __restrict__ b,
    const float* __restrict__ m, const float* __restrict__ v,
    u16* __restrict__ oh, u16* __restrict__ ol)
{
  int i = blockIdx.x*256 + threadIdx.x;
  if (i >= 2048000) return;
  int ci = i % 80;
  float s = g[ci] * rsqrtf(v[ci] + EPSBN);
  float val = (x[i] - m[ci]) * s + b[ci];
  splitstore(val, oh+i, ol+i);
}

// conv1 weights -> [co][kf], kf = kw*80+ci, padded K 400->416 with zeros
__global__ __launch_bounds__(256) void k_prep_c1w(
    const float* __restrict__ w0, u16* __restrict__ oh, u16* __restrict__ ol)
{
  int i = blockIdx.x*256 + threadIdx.x;
  if (i >= 512*416) return;
  int co = i / 416, kf = i - co*416;
  float val = 0.f;
  if (kf < 400){ int kw = kf/80, ci = kf - kw*80; val = w0[(kw*80+ci)*512 + co]; }
  splitstore(val, oh+i, ol+i);
}

// conv2 weights -> [co][kf], kf = kw*512+ci  (K=2560)
__global__ __launch_bounds__(256) void k_prep_c2w(
    const float* __restrict__ w1, u16* __restrict__ oh, u16* __restrict__ ol)
{
  int i = blockIdx.x*256 + threadIdx.x;
  if (i >= 5*512*512) return;
  int co = i & 511, ci = (i >> 9) & 511, kw = i >> 18;
  long o = (long)co*2560 + kw*512 + ci;
  splitstore(w1[i], oh+o, ol+o);
}

// gru Wx -> [l*2+d][n][k], BN2 scale folded into layer-0 rows
__global__ __launch_bounds__(256) void k_prep_wx(
    const float* __restrict__ wx, const float* __restrict__ g2, const float* __restrict__ v2,
    u16* __restrict__ oh, u16* __restrict__ ol)
{
  long i = (long)blockIdx.x*256 + threadIdx.x;
  if (i >= 6L*512*1536) return;
  int n = (int)(i % 1536); long r2 = i / 1536; int k = (int)(r2 % 512); int ld = (int)(r2 / 512);
  float s = (ld < 2) ? g2[k]*rsqrtf(v2[k]+EPSBN) : 1.f;
  long o = ((long)ld*1536 + n)*512 + k;
  splitstore(wx[i]*s, oh+o, ol+o);
}

__global__ __launch_bounds__(256) void k_prep_wh(
    const float* __restrict__ wh, u16* __restrict__ oh, u16* __restrict__ ol)
{
  long i = (long)blockIdx.x*256 + threadIdx.x;
  if (i >= 6L*512*1536) return;
  int n = (int)(i % 1536); long r2 = i / 1536; int k = (int)(r2 % 512); int ld = (int)(r2 / 512);
  long o = ((long)ld*1536 + n)*512 + k;
  splitstore(wh[i], oh+o, ol+o);
}

// gru biases: xbias[ld][n] = input bias (+ t2 @ Wx for layer 0), hbias = recurrent bias
__global__ __launch_bounds__(256) void k_prep_grub(
    const float* __restrict__ gb, const float* __restrict__ wx,
    const float* __restrict__ g2, const float* __restrict__ b2,
    const float* __restrict__ m2, const float* __restrict__ v2,
    float* __restrict__ xbias, float* __restrict__ hbias)
{
  int i = blockIdx.x*256 + threadIdx.x;
  if (i >= 6*1536) return;
  int n = i % 1536, ld = i / 1536;
  float xv = gb[(ld*2 + 0)*1536 + n];
  float hv = gb[(ld*2 + 1)*1536 + n];
  if (ld < 2){
    float acc = 0.f;
    for (int k = 0; k < 512; ++k){
      float s = g2[k]*rsqrtf(v2[k]+EPSBN);
      float t = b2[k] - m2[k]*s;
      acc += t * wx[((long)ld*512 + k)*1536 + n];
    }
    xv += acc;
  }
  xbias[i] = xv; hbias[i] = hv;
}

// fc weights with BN3 fold -> [n][k]
__global__ __launch_bounds__(256) void k_prep_fcw(
    const float* __restrict__ fw, const float* __restrict__ g3, const float* __restrict__ v3,
    u16* __restrict__ oh, u16* __restrict__ ol)
{
  int i = blockIdx.x*256 + threadIdx.x;
  if (i >= 512*512) return;
  int n = i & 511, k = i >> 9;
  float s = g3[k]*rsqrtf(v3[k]+EPSBN);
  long o = (long)n*512 + k;
  splitstore(fw[i]*s, oh+o, ol+o);
}

__global__ __launch_bounds__(256) void k_prep_fcb(
    const float* __restrict__ fw, const float* __restrict__ fb,
    const float* __restrict__ g3, const float* __restrict__ b3,
    const float* __restrict__ m3, const float* __restrict__ v3,
    float* __restrict__ ob)
{
  int n = blockIdx.x*256 + threadIdx.x;
  if (n >= 512) return;
  float acc = fb[n];
  for (int k = 0; k < 512; ++k){
    float s = g3[k]*rsqrtf(v3[k]+EPSBN);
    float t = b3[k] - m3[k]*s;
    acc += t * fw[k*512 + n];
  }
  ob[n] = acc;
}

__global__ __launch_bounds__(256) void k_prep_smw(
    const float* __restrict__ sw, u16* __restrict__ oh, u16* __restrict__ ol)
{
  long i = (long)blockIdx.x*256 + threadIdx.x;
  if (i >= 512L*6000) return;
  int n = (int)(i % 6000); int k = (int)(i / 6000);
  long o = (long)n*512 + k;
  splitstore(sw[i], oh+o, ol+o);
}

__global__ __launch_bounds__(256) void k_sumsplit(
    const float* __restrict__ a, const float* __restrict__ b,
    u16* __restrict__ oh, u16* __restrict__ ol)
{
  int i = blockIdx.x*256 + threadIdx.x;
  if (i >= 6352*512) return;
  splitstore(a[i] + b[i], oh+i, ol+i);
}

// ---------- split-bf16 GEMM: C[M,N] = A[M,K(hi/lo)] @ Bt[N,K(hi/lo)] + bias ----------
// AMODE 0: direct A[m][k].  AMODE 1: conv gather CW=80.  AMODE 2: conv gather CW=512.
// EPI 0: f32 out. EPI 1: relu -> split out. EPI 2: clip(0,20) -> split out.
template<int AMODE, int EPI>
__global__ __launch_bounds__(256,1)
void gemm_split(const u16* __restrict__ Ah, const u16* __restrict__ Al,
                const u16* __restrict__ Bh, const u16* __restrict__ Bl,
                const float* __restrict__ bias,
                float* __restrict__ outF, u16* __restrict__ outH, u16* __restrict__ outL,
                int M, int N, int K, int Kvalid, int TIN, int TOUT)
{
  constexpr int CW = (AMODE==1) ? 80 : 512;
  const int tid  = threadIdx.x;
  const int lane = tid & 63;
  const int w    = tid >> 6;
  const int wm = w >> 1, wn = w & 1;
  const int r  = lane & 15, kg = lane >> 4;
  const int m0 = blockIdx.y * 64 + wm * 32;
  const int n0 = blockIdx.x * 64 + wn * 32;

  long abase[2];
  #pragma unroll
  for (int mt = 0; mt < 2; ++mt){
    int m = m0 + mt*16 + r;
    int mc = m < M ? m : M - 1;
    if (AMODE == 0) abase[mt] = (long)mc * K;
    else { int bb = mc / TOUT; int tt = mc - bb * TOUT; abase[mt] = ((long)bb * TIN + 2*tt) * CW; }
  }
  long bbase[2];
  #pragma unroll
  for (int nt = 0; nt < 2; ++nt){
    int n = n0 + nt*16 + r;
    int nc = n < N ? n : N - 1;
    bbase[nt] = (long)nc * K;
  }

  f32x4 acc[2][2];
  #pragma unroll
  for (int a_ = 0; a_ < 2; ++a_)
    #pragma unroll
    for (int b_ = 0; b_ < 2; ++b_) acc[a_][b_] = f32x4{0.f,0.f,0.f,0.f};

  const bf16x8 zfrag = {0,0,0,0,0,0,0,0};
  const int koff = kg * 8;
  const int KT = K >> 5;
  for (int kt = 0; kt < KT; ++kt){
    int kf = kt*32 + koff;
    bf16x8 ah[2], al[2], bh[2], bl[2];
    #pragma unroll
    for (int nt = 0; nt < 2; ++nt){
      bh[nt] = *(const bf16x8*)(Bh + bbase[nt] + kf);
      bl[nt] = *(const bf16x8*)(Bl + bbase[nt] + kf);
    }
    #pragma unroll
    for (int mt = 0; mt < 2; ++mt){
      if (AMODE == 0){
        long ao = abase[mt] + kf;
        ah[mt] = *(const bf16x8*)(Ah + ao); al[mt] = *(const bf16x8*)(Al + ao);
      } else {
        if (kf < Kvalid){
          int kw = kf / CW; int ci = kf - kw*CW;
          long ao = abase[mt] + (long)kw*CW + ci;
          ah[mt] = *(const bf16x8*)(Ah + ao); al[mt] = *(const bf16x8*)(Al + ao);
        } else { ah[mt] = zfrag; al[mt] = zfrag; }
      }
    }
    #pragma unroll
    for (int mt = 0; mt < 2; ++mt)
      #pragma unroll
      for (int nt = 0; nt < 2; ++nt){
        acc[mt][nt] = MFMA(ah[mt], bh[nt], acc[mt][nt]);
        acc[mt][nt] = MFMA(ah[mt], bl[nt], acc[mt][nt]);
        acc[mt][nt] = MFMA(al[mt], bh[nt], acc[mt][nt]);
      }
  }

  #pragma unroll
  for (int nt = 0; nt < 2; ++nt){
    int n = n0 + nt*16 + r;
    if (n >= N) continue;
    float bv = bias ? bias[n] : 0.f;
    #pragma unroll
    for (int mt = 0; mt < 2; ++mt){
      #pragma unroll
      for (int q = 0; q < 4; ++q){
        int m = m0 + mt*16 + kg*4 + q;
        if (m >= M) continue;
        float v = acc[mt][nt][q] + bv;
        if (EPI == 1) v = fmaxf(v, 0.f);
        if (EPI == 2) v = fminf(fmaxf(v, 0.f), 20.f);
        long o = (long)m * N + n;
        if (EPI == 0) outF[o] = v;
        else { u16 h = f2bf(v); outH[o] = h; outL[o] = f2bf(v - bf2f(h)); }
      }
    }
  }
}

// ---------- persistent bidirectional GRU layer ----------
// 64 blocks: dir = bx>>5, slice s = bx&31 (16 h-cols each). Wh fragments held in VGPRs.
// Per-step sync: per-direction monotonic counter barrier + threadfence.
__global__ __launch_bounds__(256,1)
void gru_layer(const float* __restrict__ xp,     // [2][6352][1536]
               const u16* __restrict__ WhH, const u16* __restrict__ WhL, // [2][1536][512]
               const float* __restrict__ hbias,  // [2][1536]
               float* __restrict__ yf, float* __restrict__ yb, // [6352][512] each
               u16* __restrict__ hbH_, u16* __restrict__ hbL_, // [2][2][16][512] each plane
               u32* __restrict__ counters)       // [2]
{
  const int dir = blockIdx.x >> 5;
  const int s   = blockIdx.x & 31;
  const int tid = threadIdx.x, lane = tid & 63, w = tid >> 6;
  const int r = lane & 15, kg = lane >> 4;

  const float* xpd = xp + (long)dir * (6352L*1536);
  const u16* whh = WhH + (long)dir * (1536L*512);
  const u16* whl = WhL + (long)dir * (1536L*512);
  const float* hb = hbias + dir * 1536;
  float* y = dir ? yb : yf;
  u16* hbH = hbH_ + dir * (2*8192);
  u16* hbL = hbL_ + dir * (2*8192);
  u32* cnt = counters + dir;

  __shared__ float red[4][3][64][4];

  // persistent Wh fragments: wave w covers ktiles 4w..4w+3; gates g=0..2
  bf16x8 Bh[3][4], Bl[3][4];
  #pragma unroll
  for (int g = 0; g < 3; ++g){
    long nb = (long)(g*512 + s*16 + r) * 512;
    #pragma unroll
    for (int kk = 0; kk < 4; ++kk){
      int k = (w*4 + kk)*32 + kg*8;
      Bh[g][kk] = *(const bf16x8*)(whh + nb + k);
      Bl[g][kk] = *(const bf16x8*)(whl + nb + k);
    }
  }

  const int gb = tid >> 4, gj = tid & 15;
  const int gcol = s*16 + gj;
  const float bz = hb[gcol], br = hb[512 + gcol], bhh = hb[1024 + gcol];
  const int rl = ((gb >> 2) << 4) | gj;  // lane holding our (row=gb,col=gj)
  const int rq = gb & 3;
  float hreg = 0.f;

  for (int t = 0; t < 397; ++t){
    const int tpos = dir ? (396 - t) : t;
    const long xb_ = ((long)gb*397 + tpos)*1536 + gcol;
    float xz = xpd[xb_], xr = xpd[xb_ + 512], xh = xpd[xb_ + 1024];

    f32x4 a0 = f32x4{0.f,0.f,0.f,0.f}, a1 = a0, a2 = a0;
    if (t > 0){
      if (tid == 0){
        u32 tgt = 32u * (u32)t;
        while (__hip_atomic_load(cnt, __ATOMIC_RELAXED, __HIP_MEMORY_SCOPE_AGENT) < tgt)
          __builtin_amdgcn_s_sleep(1);
      }
      __syncthreads();
      __threadfence();  // acquire: see peers' h stores
      const u16* hH = hbH + (t & 1) * 8192;
      const u16* hL = hbL + (t & 1) * 8192;
      const int rb = r * 512 + kg * 8;
      #pragma unroll
      for (int kk = 0; kk < 4; ++kk){
        int k = (w*4 + kk) * 32;
        bf16x8 ah = *(const bf16x8*)(hH + rb + k);
        bf16x8 al = *(const bf16x8*)(hL + rb + k);
        a0 = MFMA(ah, Bh[0][kk], a0); a0 = MFMA(ah, Bl[0][kk], a0); a0 = MFMA(al, Bh[0][kk], a0);
        a1 = MFMA(ah, Bh[1][kk], a1); a1 = MFMA(ah, Bl[1][kk], a1); a1 = MFMA(al, Bh[1][kk], a1);
        a2 = MFMA(ah, Bh[2][kk], a2); a2 = MFMA(ah, Bl[2][kk], a2); a2 = MFMA(al, Bh[2][kk], a2);
      }
    }
    *(f32x4*)&red[w][0][lane][0] = a0;
    *(f32x4*)&red[w][1][lane][0] = a1;
    *(f32x4*)&red[w][2][lane][0] = a2;
    __syncthreads();
    float rz = bz, rr = br, rh = bhh;
    #pragma unroll
    for (int ww = 0; ww < 4; ++ww){
      rz += red[ww][0][rl][rq];
      rr += red[ww][1][rl][rq];
      rh += red[ww][2][rl][rq];
    }
    float z  = 1.f / (1.f + expf(-(xz + rz)));
    float rg = 1.f / (1.f + expf(-(xr + rr)));
    float hh = fmaxf(xh + rg * rh, 0.f);
    hreg = z * hreg + (1.f - z) * hh;

    y[((long)gb*397 + tpos)*512 + gcol] = hreg;
    {
      u16* oH = hbH + ((t+1) & 1) * 8192;
      u16* oL = hbL + ((t+1) & 1) * 8192;
      u16 h = f2bf(hreg);
      oH[gb*512 + gcol] = h;
      oL[gb*512 + gcol] = f2bf(hreg - bf2f(h));
    }
    __threadfence();   // release our h stores
    __syncthreads();
    if (tid == 0)
      __hip_atomic_fetch_add(cnt, 1u, __ATOMIC_RELAXED, __HIP_MEMORY_SCOPE_AGENT);
  }
}

// ---------- in-place row softmax on d_out [6352][6000] ----------
__global__ __launch_bounds__(256,1) void k_softmax(float* __restrict__ out)
{
  const int tid = threadIdx.x;
  float* prow = out + (long)blockIdx.x * 6000;
  float vals[24];
  float mx = -3.0e38f;
  #pragma unroll
  for (int i = 0; i < 24; ++i){
    int idx = tid + i*256;
    vals[i] = (idx < 6000) ? prow[idx] : -3.0e38f;
    mx = fmaxf(mx, vals[i]);
  }
  #pragma unroll
  for (int o = 32; o; o >>= 1) mx = fmaxf(mx, __shfl_xor(mx, o));
  __shared__ float sred[4];
  if ((tid & 63) == 0) sred[tid >> 6] = mx;
  __syncthreads();
  mx = fmaxf(fmaxf(sred[0], sred[1]), fmaxf(sred[2], sred[3]));
  __syncthreads();
  float sum = 0.f;
  #pragma unroll
  for (int i = 0; i < 24; ++i){
    int idx = tid + i*256;
    vals[i] = (idx < 6000) ? expf(vals[i] - mx) : 0.f;
    sum += vals[i];
  }
  #pragma unroll
  for (int o = 32; o; o >>= 1) sum += __shfl_xor(sum, o);
  if ((tid & 63) == 0) sred[tid >> 6] = sum;
  __syncthreads();
  sum = sred[0] + sred[1] + sred[2] + sred[3];
  float inv = 1.f / sum;
  #pragma unroll
  for (int i = 0; i < 24; ++i){
    int idx = tid + i*256;
    if (idx < 6000) prow[idx] = vals[i] * inv;
  }
}

// ---------- host ----------
extern "C" void kernel_launch(void* const* d_in, const int* in_sizes, int n_in,
                              void* d_out, int out_size, void* d_ws, size_t ws_size,
                              hipStream_t stream)
{
  (void)in_sizes; (void)n_in; (void)out_size; (void)ws_size;
  const float* x    = (const float*)d_in[0];
  const float* bn1g = (const float*)d_in[1];
  const float* bn1b = (const float*)d_in[2];
  const float* bn1m = (const float*)d_in[3];
  const float* bn1v = (const float*)d_in[4];
  const float* cw0  = (const float*)d_in[5];
  const float* cb0  = (const float*)d_in[6];
  const float* cw1  = (const float*)d_in[7];
  const float* cb1  = (const float*)d_in[8];
  const float* bn2g = (const float*)d_in[9];
  const float* bn2b = (const float*)d_in[10];
  const float* bn2m = (const float*)d_in[11];
  const float* bn2v = (const float*)d_in[12];
  const float* gwx  = (const float*)d_in[13];
  const float* gwh  = (const float*)d_in[14];
  const float* gbia = (const float*)d_in[15];
  const float* bn3g = (const float*)d_in[16];
  const float* bn3b = (const float*)d_in[17];
  const float* bn3m = (const float*)d_in[18];
  const float* bn3v = (const float*)d_in[19];
  const float* fcw  = (const float*)d_in[20];
  const float* fcb  = (const float*)d_in[21];
  const float* smw  = (const float*)d_in[22];
  const float* smb  = (const float*)d_in[23];

  char* p = (char*)d_ws;
  auto alloc = [&](size_t bytes)->char*{
    char* q = p; p += (bytes + 255) & ~(size_t)255; return q;
  };
  const size_t NX=2048000, NC1W=512*416, NC1O=12768L*512, NC2W=512*2560,
               NC2O=6352L*512, NWX=6L*1536*512, NXP=2L*6352*1536,
               NSMW=6000L*512, NFCW=512*512, NHB=2L*2*8192;

  u16 *xbnH=(u16*)alloc(NX*2),  *xbnL=(u16*)alloc(NX*2);
  u16 *c1wH=(u16*)alloc(NC1W*2),*c1wL=(u16*)alloc(NC1W*2);
  u16 *c1oH=(u16*)alloc(NC1O*2),*c1oL=(u16*)alloc(NC1O*2);
  u16 *c2wH=(u16*)alloc(NC2W*2),*c2wL=(u16*)alloc(NC2W*2);
  u16 *c2oH=(u16*)alloc(NC2O*2),*c2oL=(u16*)alloc(NC2O*2);
  u16 *wxH=(u16*)alloc(NWX*2),  *wxL=(u16*)alloc(NWX*2);
  u16 *whH=(u16*)alloc(NWX*2),  *whL=(u16*)alloc(NWX*2);
  float *xbias=(float*)alloc(6*1536*4), *hbias=(float*)alloc(6*1536*4);
  float *xp=(float*)alloc(NXP*4);
  float *yf=(float*)alloc(NC2O*4), *yb=(float*)alloc(NC2O*4);
  u16 *ysH=(u16*)alloc(NC2O*2), *ysL=(u16*)alloc(NC2O*2);
  u16 *fcwH=(u16*)alloc(NFCW*2),*fcwL=(u16*)alloc(NFCW*2);
  float *fcb2=(float*)alloc(512*4);
  u16 *fcoH=(u16*)alloc(NC2O*2),*fcoL=(u16*)alloc(NC2O*2);
  u16 *smwH=(u16*)alloc(NSMW*2),*smwL=(u16*)alloc(NSMW*2);
  u16 *hbH=(u16*)alloc(NHB*2),  *hbL=(u16*)alloc(NHB*2);
  u32 *counters=(u32*)alloc(64);

  hipMemsetAsync(counters, 0, 64, stream);

  k_bn1_split<<<8000,256,0,stream>>>(x, bn1g,bn1b,bn1m,bn1v, xbnH,xbnL);
  k_prep_c1w <<<832,256,0,stream>>>(cw0, c1wH,c1wL);
  k_prep_c2w <<<5120,256,0,stream>>>(cw1, c2wH,c2wL);
  k_prep_wx  <<<18432,256,0,stream>>>(gwx, bn2g,bn2v, wxH,wxL);
  k_prep_wh  <<<18432,256,0,stream>>>(gwh, whH,whL);
  k_prep_grub<<<36,256,0,stream>>>(gbia, gwx, bn2g,bn2b,bn2m,bn2v, xbias,hbias);
  k_prep_fcw <<<1024,256,0,stream>>>(fcw, bn3g,bn3v, fcwH,fcwL);
  k_prep_fcb <<<2,256,0,stream>>>(fcw,fcb, bn3g,bn3b,bn3m,bn3v, fcb2);
  k_prep_smw <<<12000,256,0,stream>>>(smw, smwH,smwL);

  // conv1: M=12768, N=512, K=416 (valid 400), stride2 gather from xbn [16*1600][80]
  gemm_split<1,1><<<dim3(8,200),256,0,stream>>>(xbnH,xbnL, c1wH,c1wL, cb0,
      nullptr, c1oH,c1oL, 12768,512,416, 400, 1600,798);
  // conv2: M=6352, N=512, K=2560, gather from c1o [12768][512]
  gemm_split<2,1><<<dim3(8,100),256,0,stream>>>(c1oH,c1oL, c2wH,c2wL, cb1,
      nullptr, c2oH,c2oL, 6352,512,2560, 2560, 798,397);

  const u16 *aH = c2oH, *aL = c2oL;
  for (int l = 0; l < 3; ++l){
    for (int d = 0; d < 2; ++d){
      gemm_split<0,0><<<dim3(24,100),256,0,stream>>>(aH,aL,
          wxH + (size_t)(l*2+d)*786432, wxL + (size_t)(l*2+d)*786432,
          xbias + (l*2+d)*1536,
          xp + (size_t)d*9756672, nullptr,nullptr,
          6352,1536,512, 512, 0,0);
    }
    gru_layer<<<64,256,0,stream>>>(xp,
        whH + (size_t)l*2*786432, whL + (size_t)l*2*786432,
        hbias + l*2*1536, yf,yb, hbH,hbL, counters + l*2);
    k_sumsplit<<<12704,256,0,stream>>>(yf,yb, ysH,ysL);
    aH = ysH; aL = ysL;
  }

  // fc: clip(relu(x@W+b),20) -> split
  gemm_split<0,2><<<dim3(8,100),256,0,stream>>>(ysH,ysL, fcwH,fcwL, fcb2,
      nullptr, fcoH,fcoL, 6352,512,512, 512, 0,0);
  // logits -> d_out (f32), then in-place softmax
  gemm_split<0,0><<<dim3(94,100),256,0,stream>>>(fcoH,fcoL, smwH,smwL, smb,
      (float*)d_out, nullptr,nullptr, 6352,6000,512, 512, 0,0);
  k_softmax<<<6352,256,0,stream>>>((float*)d_out);
}

// Round 4
// 6039.240 us; speedup vs baseline: 2.9046x; 2.8919x over previous
//
#include <hip/hip_runtime.h>
#include <math.h>

// ---------- types / helpers ----------
using bf16x8 = __attribute__((ext_vector_type(8))) short;
using f32x4  = __attribute__((ext_vector_type(4))) float;
typedef unsigned short u16;
typedef unsigned int   u32;

#define EPSBN 1e-3f

__device__ __forceinline__ u16 f2bf(float f){
  union { float f; u32 u; } c; c.f = f;
  u32 u = c.u + 0x7fffu + ((c.u >> 16) & 1u);
  return (u16)(u >> 16);
}
__device__ __forceinline__ float bf2f(u16 b){
  union { u32 u; float f; } c; c.u = ((u32)b) << 16; return c.f;
}
__device__ __forceinline__ void splitstore(float v, u16* ph, u16* pl){
  u16 h = f2bf(v); *ph = h; *pl = f2bf(v - bf2f(h));
}
__device__ __forceinline__ f32x4 MFMA(bf16x8 a, bf16x8 b, f32x4 c){
  return __builtin_amdgcn_mfma_f32_16x16x32_bf16(a, b, c, 0, 0, 0);
}

// coherent-point (cross-XCD visible) accesses: sc0 sc1 bypass L1/L2, hit IF$.
__device__ __forceinline__ bf16x8 ld128_sys(const u16* p){
  bf16x8 r;
  asm volatile("global_load_dwordx4 %0, %1, off sc0 sc1" : "=v"(r) : "v"(p) : "memory");
  return r;
}
__device__ __forceinline__ void st16_sys(u16* p, u16 v){
  u32 vv = v;
  asm volatile("global_store_short %0, %1, off sc0 sc1" :: "v"(p), "v"(vv) : "memory");
}

// ---------- prep kernels (BN folding, transpose, bf16 hi/lo split) ----------
__global__ __launch_bounds__(256) void k_bn1_split(
    const float* __restrict__ x, const float* __restrict__ g, const float* __restrict__ b,
    const float* __restrict__ m, const float* __restrict__ v,
    u16* __restrict__ oh, u16* __restrict__ ol)
{
  int i = blockIdx.x*256 + threadIdx.x;
  if (i >= 2048000) return;
  int ci = i % 80;
  float s = g[ci] * rsqrtf(v[ci] + EPSBN);
  float val = (x[i] - m[ci]) * s + b[ci];
  splitstore(val, oh+i, ol+i);
}

// conv1 weights -> [co][kf], kf = kw*80+ci, padded K 400->416 with zeros
__global__ __launch_bounds__(256) void k_prep_c1w(
    const float* __restrict__ w0, u16* __restrict__ oh, u16* __restrict__ ol)
{
  int i = blockIdx.x*256 + threadIdx.x;
  if (i >= 512*416) return;
  int co = i / 416, kf = i - co*416;
  float val = 0.f;
  if (kf < 400){ int kw = kf/80, ci = kf - kw*80; val = w0[(kw*80+ci)*512 + co]; }
  splitstore(val, oh+i, ol+i);
}

// conv2 weights -> [co][kf], kf = kw*512+ci  (K=2560)
__global__ __launch_bounds__(256) void k_prep_c2w(
    const float* __restrict__ w1, u16* __restrict__ oh, u16* __restrict__ ol)
{
  int i = blockIdx.x*256 + threadIdx.x;
  if (i >= 5*512*512) return;
  int co = i & 511, ci = (i >> 9) & 511, kw = i >> 18;
  long o = (long)co*2560 + kw*512 + ci;
  splitstore(w1[i], oh+o, ol+o);
}

// gru Wx -> [l*2+d][n][k], BN2 scale folded into layer-0 rows
__global__ __launch_bounds__(256) void k_prep_wx(
    const float* __restrict__ wx, const float* __restrict__ g2, const float* __restrict__ v2,
    u16* __restrict__ oh, u16* __restrict__ ol)
{
  long i = (long)blockIdx.x*256 + threadIdx.x;
  if (i >= 6L*512*1536) return;
  int n = (int)(i % 1536); long r2 = i / 1536; int k = (int)(r2 % 512); int ld = (int)(r2 / 512);
  float s = (ld < 2) ? g2[k]*rsqrtf(v2[k]+EPSBN) : 1.f;
  long o = ((long)ld*1536 + n)*512 + k;
  splitstore(wx[i]*s, oh+o, ol+o);
}

__global__ __launch_bounds__(256) void k_prep_wh(
    const float* __restrict__ wh, u16* __restrict__ oh, u16* __restrict__ ol)
{
  long i = (long)blockIdx.x*256 + threadIdx.x;
  if (i >= 6L*512*1536) return;
  int n = (int)(i % 1536); long r2 = i / 1536; int k = (int)(r2 % 512); int ld = (int)(r2 / 512);
  long o = ((long)ld*1536 + n)*512 + k;
  splitstore(wh[i], oh+o, ol+o);
}

// gru biases: xbias[ld][n] = input bias (+ t2 @ Wx for layer 0), hbias = recurrent bias
__global__ __launch_bounds__(256) void k_prep_grub(
    const float* __restrict__ gb, const float* __restrict__ wx,
    const float* __restrict__ g2, const float* __restrict__ b2,
    const float* __restrict__ m2, const float* __restrict__ v2,
    float* __restrict__ xbias, float* __restrict__ hbias)
{
  int i = blockIdx.x*256 + threadIdx.x;
  if (i >= 6*1536) return;
  int n = i % 1536, ld = i / 1536;
  float xv = gb[(ld*2 + 0)*1536 + n];
  float hv = gb[(ld*2 + 1)*1536 + n];
  if (ld < 2){
    float acc = 0.f;
    for (int k = 0; k < 512; ++k){
      float s = g2[k]*rsqrtf(v2[k]+EPSBN);
      float t = b2[k] - m2[k]*s;
      acc += t * wx[((long)ld*512 + k)*1536 + n];
    }
    xv += acc;
  }
  xbias[i] = xv; hbias[i] = hv;
}

// fc weights with BN3 fold -> [n][k]
__global__ __launch_bounds__(256) void k_prep_fcw(
    const float* __restrict__ fw, const float* __restrict__ g3, const float* __restrict__ v3,
    u16* __restrict__ oh, u16* __restrict__ ol)
{
  int i = blockIdx.x*256 + threadIdx.x;
  if (i >= 512*512) return;
  int n = i & 511, k = i >> 9;
  float s = g3[k]*rsqrtf(v3[k]+EPSBN);
  long o = (long)n*512 + k;
  splitstore(fw[i]*s, oh+o, ol+o);
}

__global__ __launch_bounds__(256) void k_prep_fcb(
    const float* __restrict__ fw, const float* __restrict__ fb,
    const float* __restrict__ g3, const float* __restrict__ b3,
    const float* __restrict__ m3, const float* __restrict__ v3,
    float* __restrict__ ob)
{
  int n = blockIdx.x*256 + threadIdx.x;
  if (n >= 512) return;
  float acc = fb[n];
  for (int k = 0; k < 512; ++k){
    float s = g3[k]*rsqrtf(v3[k]+EPSBN);
    float t = b3[k] - m3[k]*s;
    acc += t * fw[k*512 + n];
  }
  ob[n] = acc;
}

__global__ __launch_bounds__(256) void k_prep_smw(
    const float* __restrict__ sw, u16* __restrict__ oh, u16* __restrict__ ol)
{
  long i = (long)blockIdx.x*256 + threadIdx.x;
  if (i >= 512L*6000) return;
  int n = (int)(i % 6000); int k = (int)(i / 6000);
  long o = (long)n*512 + k;
  splitstore(sw[i], oh+o, ol+o);
}

__global__ __launch_bounds__(256) void k_sumsplit(
    const float* __restrict__ a, const float* __restrict__ b,
    u16* __restrict__ oh, u16* __restrict__ ol)
{
  int i = blockIdx.x*256 + threadIdx.x;
  if (i >= 6352*512) return;
  splitstore(a[i] + b[i], oh+i, ol+i);
}

// ---------- split-bf16 GEMM: C[M,N] = A[M,K(hi/lo)] @ Bt[N,K(hi/lo)] + bias ----------
// AMODE 0: direct A[m][k].  AMODE 1: conv gather CW=80.  AMODE 2: conv gather CW=512.
// EPI 0: f32 out. EPI 1: relu -> split out. EPI 2: clip(0,20) -> split out.
template<int AMODE, int EPI>
__global__ __launch_bounds__(256,1)
void gemm_split(const u16* __restrict__ Ah, const u16* __restrict__ Al,
                const u16* __restrict__ Bh, const u16* __restrict__ Bl,
                const float* __restrict__ bias,
                float* __restrict__ outF, u16* __restrict__ outH, u16* __restrict__ outL,
                int M, int N, int K, int Kvalid, int TIN, int TOUT)
{
  constexpr int CW = (AMODE==1) ? 80 : 512;
  const int tid  = threadIdx.x;
  const int lane = tid & 63;
  const int w    = tid >> 6;
  const int wm = w >> 1, wn = w & 1;
  const int r  = lane & 15, kg = lane >> 4;
  const int m0 = blockIdx.y * 64 + wm * 32;
  const int n0 = blockIdx.x * 64 + wn * 32;

  long abase[2];
  #pragma unroll
  for (int mt = 0; mt < 2; ++mt){
    int m = m0 + mt*16 + r;
    int mc = m < M ? m : M - 1;
    if (AMODE == 0) abase[mt] = (long)mc * K;
    else { int bb = mc / TOUT; int tt = mc - bb * TOUT; abase[mt] = ((long)bb * TIN + 2*tt) * CW; }
  }
  long bbase[2];
  #pragma unroll
  for (int nt = 0; nt < 2; ++nt){
    int n = n0 + nt*16 + r;
    int nc = n < N ? n : N - 1;
    bbase[nt] = (long)nc * K;
  }

  f32x4 acc[2][2];
  #pragma unroll
  for (int a_ = 0; a_ < 2; ++a_)
    #pragma unroll
    for (int b_ = 0; b_ < 2; ++b_) acc[a_][b_] = f32x4{0.f,0.f,0.f,0.f};

  const bf16x8 zfrag = {0,0,0,0,0,0,0,0};
  const int koff = kg * 8;
  const int KT = K >> 5;
  for (int kt = 0; kt < KT; ++kt){
    int kf = kt*32 + koff;
    bf16x8 ah[2], al[2], bh[2], bl[2];
    #pragma unroll
    for (int nt = 0; nt < 2; ++nt){
      bh[nt] = *(const bf16x8*)(Bh + bbase[nt] + kf);
      bl[nt] = *(const bf16x8*)(Bl + bbase[nt] + kf);
    }
    #pragma unroll
    for (int mt = 0; mt < 2; ++mt){
      if (AMODE == 0){
        long ao = abase[mt] + kf;
        ah[mt] = *(const bf16x8*)(Ah + ao); al[mt] = *(const bf16x8*)(Al + ao);
      } else {
        if (kf < Kvalid){
          int kw = kf / CW; int ci = kf - kw*CW;
          long ao = abase[mt] + (long)kw*CW + ci;
          ah[mt] = *(const bf16x8*)(Ah + ao); al[mt] = *(const bf16x8*)(Al + ao);
        } else { ah[mt] = zfrag; al[mt] = zfrag; }
      }
    }
    #pragma unroll
    for (int mt = 0; mt < 2; ++mt)
      #pragma unroll
      for (int nt = 0; nt < 2; ++nt){
        acc[mt][nt] = MFMA(ah[mt], bh[nt], acc[mt][nt]);
        acc[mt][nt] = MFMA(ah[mt], bl[nt], acc[mt][nt]);
        acc[mt][nt] = MFMA(al[mt], bh[nt], acc[mt][nt]);
      }
  }

  #pragma unroll
  for (int nt = 0; nt < 2; ++nt){
    int n = n0 + nt*16 + r;
    if (n >= N) continue;
    float bv = bias ? bias[n] : 0.f;
    #pragma unroll
    for (int mt = 0; mt < 2; ++mt){
      #pragma unroll
      for (int q = 0; q < 4; ++q){
        int m = m0 + mt*16 + kg*4 + q;
        if (m >= M) continue;
        float v = acc[mt][nt][q] + bv;
        if (EPI == 1) v = fmaxf(v, 0.f);
        if (EPI == 2) v = fminf(fmaxf(v, 0.f), 20.f);
        long o = (long)m * N + n;
        if (EPI == 0) outF[o] = v;
        else { u16 h = f2bf(v); outH[o] = h; outL[o] = f2bf(v - bf2f(h)); }
      }
    }
  }
}

// ---------- persistent bidirectional GRU layer ----------
// 64 blocks: dir = bx>>5, slice s = bx&31 (16 h-cols each). Wh fragments pinned in VGPRs.
// Per-step sync: per-block monotonic flag (sc1 store), consumers poll 32 flags in
// parallel with 32 lanes. h exchange via sc0/sc1 coherent-point accesses — no cache
// invalidation, no atomic RMW serialization.
__global__ __launch_bounds__(256,1)
void gru_layer(const float* __restrict__ xp,     // [2][6352][1536]
               const u16* __restrict__ WhH, const u16* __restrict__ WhL, // [2][1536][512]
               const float* __restrict__ hbias,  // [2][1536]
               float* __restrict__ yf, float* __restrict__ yb, // [6352][512] each
               u16* __restrict__ hbH_, u16* __restrict__ hbL_, // [2][2][16][512] each plane
               u32* __restrict__ flags)          // [2][32] steps-completed per block
{
  const int dir = blockIdx.x >> 5;
  const int s   = blockIdx.x & 31;
  const int tid = threadIdx.x, lane = tid & 63, w = tid >> 6;
  const int r = lane & 15, kg = lane >> 4;

  const float* xpd = xp + (long)dir * (6352L*1536);
  const u16* whh = WhH + (long)dir * (1536L*512);
  const u16* whl = WhL + (long)dir * (1536L*512);
  const float* hb = hbias + dir * 1536;
  float* y = dir ? yb : yf;
  u16* hbH = hbH_ + dir * (2*8192);
  u16* hbL = hbL_ + dir * (2*8192);
  u32* flg = flags + dir * 32;

  __shared__ float red[4][3][64][4];

  // persistent Wh fragments: wave w covers ktiles 4w..4w+3; gates g=0..2
  bf16x8 Bh[3][4], Bl[3][4];
  #pragma unroll
  for (int g = 0; g < 3; ++g){
    long nb = (long)(g*512 + s*16 + r) * 512;
    #pragma unroll
    for (int kk = 0; kk < 4; ++kk){
      int k = (w*4 + kk)*32 + kg*8;
      Bh[g][kk] = *(const bf16x8*)(whh + nb + k);
      Bl[g][kk] = *(const bf16x8*)(whl + nb + k);
    }
  }
  // pin fragments in VGPRs (asm-defined values can't be rematerialized via reload)
  #pragma unroll
  for (int g = 0; g < 3; ++g)
    #pragma unroll
    for (int kk = 0; kk < 4; ++kk)
      asm volatile("" : "+v"(Bh[g][kk]), "+v"(Bl[g][kk]));

  const int gb = tid >> 4, gj = tid & 15;
  const int gcol = s*16 + gj;
  const float bz = hb[gcol], br = hb[512 + gcol], bhh = hb[1024 + gcol];
  const int rl = ((gb >> 2) << 4) | gj;  // lane holding our (row=gb,col=gj)
  const int rq = gb & 3;
  const int rb = r * 512 + kg * 8;
  float hreg = 0.f;

  for (int t = 0; t < 397; ++t){
    const int tpos = dir ? (396 - t) : t;
    const long xb_ = ((long)gb*397 + tpos)*1536 + gcol;
    float xz = xpd[xb_], xr = xpd[xb_ + 512], xh = xpd[xb_ + 1024];

    f32x4 a0 = f32x4{0.f,0.f,0.f,0.f}, a1 = a0, a2 = a0;
    if (t > 0){
      if (w == 0){
        const u32 tgt = (u32)t;
        for (;;){
          int done = 1;
          if (lane < 32)
            done = (__hip_atomic_load(flg + lane, __ATOMIC_RELAXED,
                                      __HIP_MEMORY_SCOPE_AGENT) >= tgt);
          if (__all(done)) break;
        }
      }
      __syncthreads();
      const u16* hH = hbH + (t & 1) * 8192;
      const u16* hL = hbL + (t & 1) * 8192;
      bf16x8 ah[4], al[4];
      #pragma unroll
      for (int kk = 0; kk < 4; ++kk){
        int k = (w*4 + kk) * 32;
        ah[kk] = ld128_sys(hH + rb + k);
        al[kk] = ld128_sys(hL + rb + k);
      }
      asm volatile("s_waitcnt vmcnt(0)" ::: "memory");
      __builtin_amdgcn_sched_barrier(0);
      #pragma unroll
      for (int kk = 0; kk < 4; ++kk){
        a0 = MFMA(ah[kk], Bh[0][kk], a0); a0 = MFMA(ah[kk], Bl[0][kk], a0); a0 = MFMA(al[kk], Bh[0][kk], a0);
        a1 = MFMA(ah[kk], Bh[1][kk], a1); a1 = MFMA(ah[kk], Bl[1][kk], a1); a1 = MFMA(al[kk], Bh[1][kk], a1);
        a2 = MFMA(ah[kk], Bh[2][kk], a2); a2 = MFMA(ah[kk], Bl[2][kk], a2); a2 = MFMA(al[kk], Bh[2][kk], a2);
      }
    }
    *(f32x4*)&red[w][0][lane][0] = a0;
    *(f32x4*)&red[w][1][lane][0] = a1;
    *(f32x4*)&red[w][2][lane][0] = a2;
    __syncthreads();
    float rz = bz, rr = br, rh = bhh;
    #pragma unroll
    for (int ww = 0; ww < 4; ++ww){
      rz += red[ww][0][rl][rq];
      rr += red[ww][1][rl][rq];
      rh += red[ww][2][rl][rq];
    }
    float z  = 1.f / (1.f + expf(-(xz + rz)));
    float rg = 1.f / (1.f + expf(-(xr + rr)));
    float hh = fmaxf(xh + rg * rh, 0.f);
    hreg = z * hreg + (1.f - z) * hh;

    // release: coherent h stores -> drain -> block barrier -> flag post
    {
      u16* oH = hbH + ((t+1) & 1) * 8192;
      u16* oL = hbL + ((t+1) & 1) * 8192;
      u16 hhi = f2bf(hreg);
      u16 hlo = f2bf(hreg - bf2f(hhi));
      st16_sys(oH + gb*512 + gcol, hhi);
      st16_sys(oL + gb*512 + gcol, hlo);
    }
    asm volatile("s_waitcnt vmcnt(0)" ::: "memory");
    __syncthreads();
    if (tid == 0)
      __hip_atomic_store(flg + s, (u32)(t + 1), __ATOMIC_RELAXED,
                         __HIP_MEMORY_SCOPE_AGENT);
    y[((long)gb*397 + tpos)*512 + gcol] = hreg;  // off critical path
  }
}

// ---------- in-place row softmax on d_out [6352][6000] ----------
__global__ __launch_bounds__(256,1) void k_softmax(float* __restrict__ out)
{
  const int tid = threadIdx.x;
  float* prow = out + (long)blockIdx.x * 6000;
  float vals[24];
  float mx = -3.0e38f;
  #pragma unroll
  for (int i = 0; i < 24; ++i){
    int idx = tid + i*256;
    vals[i] = (idx < 6000) ? prow[idx] : -3.0e38f;
    mx = fmaxf(mx, vals[i]);
  }
  #pragma unroll
  for (int o = 32; o; o >>= 1) mx = fmaxf(mx, __shfl_xor(mx, o));
  __shared__ float sred[4];
  if ((tid & 63) == 0) sred[tid >> 6] = mx;
  __syncthreads();
  mx = fmaxf(fmaxf(sred[0], sred[1]), fmaxf(sred[2], sred[3]));
  __syncthreads();
  float sum = 0.f;
  #pragma unroll
  for (int i = 0; i < 24; ++i){
    int idx = tid + i*256;
    vals[i] = (idx < 6000) ? expf(vals[i] - mx) : 0.f;
    sum += vals[i];
  }
  #pragma unroll
  for (int o = 32; o; o >>= 1) sum += __shfl_xor(sum, o);
  if ((tid & 63) == 0) sred[tid >> 6] = sum;
  __syncthreads();
  sum = sred[0] + sred[1] + sred[2] + sred[3];
  float inv = 1.f / sum;
  #pragma unroll
  for (int i = 0; i < 24; ++i){
    int idx = tid + i*256;
    if (idx < 6000) prow[idx] = vals[i] * inv;
  }
}

// ---------- host ----------
extern "C" void kernel_launch(void* const* d_in, const int* in_sizes, int n_in,
                              void* d_out, int out_size, void* d_ws, size_t ws_size,
                              hipStream_t stream)
{
  (void)in_sizes; (void)n_in; (void)out_size; (void)ws_size;
  const float* x    = (const float*)d_in[0];
  const float* bn1g = (const float*)d_in[1];
  const float* bn1b = (const float*)d_in[2];
  const float* bn1m = (const float*)d_in[3];
  const float* bn1v = (const float*)d_in[4];
  const float* cw0  = (const float*)d_in[5];
  const float* cb0  = (const float*)d_in[6];
  const float* cw1  = (const float*)d_in[7];
  const float* cb1  = (const float*)d_in[8];
  const float* bn2g = (const float*)d_in[9];
  const float* bn2b = (const float*)d_in[10];
  const float* bn2m = (const float*)d_in[11];
  const float* bn2v = (const float*)d_in[12];
  const float* gwx  = (const float*)d_in[13];
  const float* gwh  = (const float*)d_in[14];
  const float* gbia = (const float*)d_in[15];
  const float* bn3g = (const float*)d_in[16];
  const float* bn3b = (const float*)d_in[17];
  const float* bn3m = (const float*)d_in[18];
  const float* bn3v = (const float*)d_in[19];
  const float* fcw  = (const float*)d_in[20];
  const float* fcb  = (const float*)d_in[21];
  const float* smw  = (const float*)d_in[22];
  const float* smb  = (const float*)d_in[23];

  char* p = (char*)d_ws;
  auto alloc = [&](size_t bytes)->char*{
    char* q = p; p += (bytes + 255) & ~(size_t)255; return q;
  };
  const size_t NX=2048000, NC1W=512*416, NC1O=12768L*512, NC2W=512*2560,
               NC2O=6352L*512, NWX=6L*1536*512, NXP=2L*6352*1536,
               NSMW=6000L*512, NFCW=512*512, NHB=2L*2*8192;

  u16 *xbnH=(u16*)alloc(NX*2),  *xbnL=(u16*)alloc(NX*2);
  u16 *c1wH=(u16*)alloc(NC1W*2),*c1wL=(u16*)alloc(NC1W*2);
  u16 *c1oH=(u16*)alloc(NC1O*2),*c1oL=(u16*)alloc(NC1O*2);
  u16 *c2wH=(u16*)alloc(NC2W*2),*c2wL=(u16*)alloc(NC2W*2);
  u16 *c2oH=(u16*)alloc(NC2O*2),*c2oL=(u16*)alloc(NC2O*2);
  u16 *wxH=(u16*)alloc(NWX*2),  *wxL=(u16*)alloc(NWX*2);
  u16 *whH=(u16*)alloc(NWX*2),  *whL=(u16*)alloc(NWX*2);
  float *xbias=(float*)alloc(6*1536*4), *hbias=(float*)alloc(6*1536*4);
  float *xp=(float*)alloc(NXP*4);
  float *yf=(float*)alloc(NC2O*4), *yb=(float*)alloc(NC2O*4);
  u16 *ysH=(u16*)alloc(NC2O*2), *ysL=(u16*)alloc(NC2O*2);
  u16 *fcwH=(u16*)alloc(NFCW*2),*fcwL=(u16*)alloc(NFCW*2);
  float *fcb2=(float*)alloc(512*4);
  u16 *fcoH=(u16*)alloc(NC2O*2),*fcoL=(u16*)alloc(NC2O*2);
  u16 *smwH=(u16*)alloc(NSMW*2),*smwL=(u16*)alloc(NSMW*2);
  u16 *hbH=(u16*)alloc(NHB*2),  *hbL=(u16*)alloc(NHB*2);
  u32 *flags=(u32*)alloc(3*64*4);   // [layer][dir][32]

  hipMemsetAsync(flags, 0, 3*64*4, stream);

  k_bn1_split<<<8000,256,0,stream>>>(x, bn1g,bn1b,bn1m,bn1v, xbnH,xbnL);
  k_prep_c1w <<<832,256,0,stream>>>(cw0, c1wH,c1wL);
  k_prep_c2w <<<5120,256,0,stream>>>(cw1, c2wH,c2wL);
  k_prep_wx  <<<18432,256,0,stream>>>(gwx, bn2g,bn2v, wxH,wxL);
  k_prep_wh  <<<18432,256,0,stream>>>(gwh, whH,whL);
  k_prep_grub<<<36,256,0,stream>>>(gbia, gwx, bn2g,bn2b,bn2m,bn2v, xbias,hbias);
  k_prep_fcw <<<1024,256,0,stream>>>(fcw, bn3g,bn3v, fcwH,fcwL);
  k_prep_fcb <<<2,256,0,stream>>>(fcw,fcb, bn3g,bn3b,bn3m,bn3v, fcb2);
  k_prep_smw <<<12000,256,0,stream>>>(smw, smwH,smwL);

  // conv1: M=12768, N=512, K=416 (valid 400), stride2 gather from xbn [16*1600][80]
  gemm_split<1,1><<<dim3(8,200),256,0,stream>>>(xbnH,xbnL, c1wH,c1wL, cb0,
      nullptr, c1oH,c1oL, 12768,512,416, 400, 1600,798);
  // conv2: M=6352, N=512, K=2560, gather from c1o [12768][512]
  gemm_split<2,1><<<dim3(8,100),256,0,stream>>>(c1oH,c1oL, c2wH,c2wL, cb1,
      nullptr, c2oH,c2oL, 6352,512,2560, 2560, 798,397);

  const u16 *aH = c2oH, *aL = c2oL;
  for (int l = 0; l < 3; ++l){
    for (int d = 0; d < 2; ++d){
      gemm_split<0,0><<<dim3(24,100),256,0,stream>>>(aH,aL,
          wxH + (size_t)(l*2+d)*786432, wxL + (size_t)(l*2+d)*786432,
          xbias + (l*2+d)*1536,
          xp + (size_t)d*9756672, nullptr,nullptr,
          6352,1536,512, 512, 0,0);
    }
    gru_layer<<<64,256,0,stream>>>(xp,
        whH + (size_t)l*2*786432, whL + (size_t)l*2*786432,
        hbias + l*2*1536, yf,yb, hbH,hbL, flags + l*64);
    k_sumsplit<<<12704,256,0,stream>>>(yf,yb, ysH,ysL);
    aH = ysH; aL = ysL;
  }

  // fc: clip(relu(x@W+b),20) -> split
  gemm_split<0,2><<<dim3(8,100),256,0,stream>>>(ysH,ysL, fcwH,fcwL, fcb2,
      nullptr, fcoH,fcoL, 6352,512,512, 512, 0,0);
  // logits -> d_out (f32), then in-place softmax
  gemm_split<0,0><<<dim3(94,100),256,0,stream>>>(fcoH,fcoL, smwH,smwL, smb,
      (float*)d_out, nullptr,nullptr, 6352,6000,512, 512, 0,0);
  k_softmax<<<6352,256,0,stream>>>((float*)d_out);
}

// Round 5
// 5924.163 us; speedup vs baseline: 2.9610x; 1.0194x over previous
//
#include <hip/hip_runtime.h>
#include <math.h>

// ---------- types / helpers ----------
using bf16x8 = __attribute__((ext_vector_type(8))) short;
using f32x4  = __attribute__((ext_vector_type(4))) float;
typedef unsigned short u16;
typedef unsigned int   u32;

#define EPSBN 1e-3f

__device__ __forceinline__ u16 f2bf(float f){
  union { float f; u32 u; } c; c.f = f;
  u32 u = c.u + 0x7fffu + ((c.u >> 16) & 1u);
  return (u16)(u >> 16);
}
__device__ __forceinline__ float bf2f(u16 b){
  union { u32 u; float f; } c; c.u = ((u32)b) << 16; return c.f;
}
__device__ __forceinline__ void splitstore(float v, u16* ph, u16* pl){
  u16 h = f2bf(v); *ph = h; *pl = f2bf(v - bf2f(h));
}
__device__ __forceinline__ f32x4 MFMA(bf16x8 a, bf16x8 b, f32x4 c){
  return __builtin_amdgcn_mfma_f32_16x16x32_bf16(a, b, c, 0, 0, 0);
}

// coherent-point (cross-XCD visible) accesses: sc0 sc1 bypass L1/L2, hit IF$.
__device__ __forceinline__ bf16x8 ld128_sys(const u16* p){
  bf16x8 r;
  asm volatile("global_load_dwordx4 %0, %1, off sc0 sc1" : "=v"(r) : "v"(p) : "memory");
  return r;
}
__device__ __forceinline__ void st16_sys(u16* p, u16 v){
  u32 vv = v;
  asm volatile("global_store_short %0, %1, off sc0 sc1" :: "v"(p), "v"(vv) : "memory");
}

// ---------- prep kernels (BN folding, transpose, bf16 hi/lo split) ----------
__global__ __launch_bounds__(256) void k_bn1_split(
    const float* __restrict__ x, const float* __restrict__ g, const float* __restrict__ b,
    const float* __restrict__ m, const float* __restrict__ v,
    u16* __restrict__ oh, u16* __restrict__ ol)
{
  int i = blockIdx.x*256 + threadIdx.x;
  if (i >= 2048000) return;
  int ci = i % 80;
  float s = g[ci] * rsqrtf(v[ci] + EPSBN);
  float val = (x[i] - m[ci]) * s + b[ci];
  splitstore(val, oh+i, ol+i);
}

// conv1 weights -> [co][kf], kf = kw*80+ci, padded K 400->416 with zeros
__global__ __launch_bounds__(256) void k_prep_c1w(
    const float* __restrict__ w0, u16* __restrict__ oh, u16* __restrict__ ol)
{
  int i = blockIdx.x*256 + threadIdx.x;
  if (i >= 512*416) return;
  int co = i / 416, kf = i - co*416;
  float val = 0.f;
  if (kf < 400){ int kw = kf/80, ci = kf - kw*80; val = w0[(kw*80+ci)*512 + co]; }
  splitstore(val, oh+i, ol+i);
}

// conv2 weights -> [co][kf], kf = kw*512+ci  (K=2560)
__global__ __launch_bounds__(256) void k_prep_c2w(
    const float* __restrict__ w1, u16* __restrict__ oh, u16* __restrict__ ol)
{
  int i = blockIdx.x*256 + threadIdx.x;
  if (i >= 5*512*512) return;
  int co = i & 511, ci = (i >> 9) & 511, kw = i >> 18;
  long o = (long)co*2560 + kw*512 + ci;
  splitstore(w1[i], oh+o, ol+o);
}

// gru Wx -> [l*2+d][n][k], BN2 scale folded into layer-0 rows
__global__ __launch_bounds__(256) void k_prep_wx(
    const float* __restrict__ wx, const float* __restrict__ g2, const float* __restrict__ v2,
    u16* __restrict__ oh, u16* __restrict__ ol)
{
  long i = (long)blockIdx.x*256 + threadIdx.x;
  if (i >= 6L*512*1536) return;
  int n = (int)(i % 1536); long r2 = i / 1536; int k = (int)(r2 % 512); int ld = (int)(r2 / 512);
  float s = (ld < 2) ? g2[k]*rsqrtf(v2[k]+EPSBN) : 1.f;
  long o = ((long)ld*1536 + n)*512 + k;
  splitstore(wx[i]*s, oh+o, ol+o);
}

__global__ __launch_bounds__(256) void k_prep_wh(
    const float* __restrict__ wh, u16* __restrict__ oh, u16* __restrict__ ol)
{
  long i = (long)blockIdx.x*256 + threadIdx.x;
  if (i >= 6L*512*1536) return;
  int n = (int)(i % 1536); long r2 = i / 1536; int k = (int)(r2 % 512); int ld = (int)(r2 / 512);
  long o = ((long)ld*1536 + n)*512 + k;
  splitstore(wh[i], oh+o, ol+o);
}

// gru biases: xbias[ld][n] = input bias (+ t2 @ Wx for layer 0), hbias = recurrent bias
__global__ __launch_bounds__(256) void k_prep_grub(
    const float* __restrict__ gb, const float* __restrict__ wx,
    const float* __restrict__ g2, const float* __restrict__ b2,
    const float* __restrict__ m2, const float* __restrict__ v2,
    float* __restrict__ xbias, float* __restrict__ hbias)
{
  int i = blockIdx.x*256 + threadIdx.x;
  if (i >= 6*1536) return;
  int n = i % 1536, ld = i / 1536;
  float xv = gb[(ld*2 + 0)*1536 + n];
  float hv = gb[(ld*2 + 1)*1536 + n];
  if (ld < 2){
    float acc = 0.f;
    for (int k = 0; k < 512; ++k){
      float s = g2[k]*rsqrtf(v2[k]+EPSBN);
      float t = b2[k] - m2[k]*s;
      acc += t * wx[((long)ld*512 + k)*1536 + n];
    }
    xv += acc;
  }
  xbias[i] = xv; hbias[i] = hv;
}

// fc weights with BN3 fold -> [n][k]
__global__ __launch_bounds__(256) void k_prep_fcw(
    const float* __restrict__ fw, const float* __restrict__ g3, const float* __restrict__ v3,
    u16* __restrict__ oh, u16* __restrict__ ol)
{
  int i = blockIdx.x*256 + threadIdx.x;
  if (i >= 512*512) return;
  int n = i & 511, k = i >> 9;
  float s = g3[k]*rsqrtf(v3[k]+EPSBN);
  long o = (long)n*512 + k;
  splitstore(fw[i]*s, oh+o, ol+o);
}

__global__ __launch_bounds__(256) void k_prep_fcb(
    const float* __restrict__ fw, const float* __restrict__ fb,
    const float* __restrict__ g3, const float* __restrict__ b3,
    const float* __restrict__ m3, const float* __restrict__ v3,
    float* __restrict__ ob)
{
  int n = blockIdx.x*256 + threadIdx.x;
  if (n >= 512) return;
  float acc = fb[n];
  for (int k = 0; k < 512; ++k){
    float s = g3[k]*rsqrtf(v3[k]+EPSBN);
    float t = b3[k] - m3[k]*s;
    acc += t * fw[k*512 + n];
  }
  ob[n] = acc;
}

__global__ __launch_bounds__(256) void k_prep_smw(
    const float* __restrict__ sw, u16* __restrict__ oh, u16* __restrict__ ol)
{
  long i = (long)blockIdx.x*256 + threadIdx.x;
  if (i >= 512L*6000) return;
  int n = (int)(i % 6000); int k = (int)(i / 6000);
  long o = (long)n*512 + k;
  splitstore(sw[i], oh+o, ol+o);
}

__global__ __launch_bounds__(256) void k_sumsplit(
    const float* __restrict__ a, const float* __restrict__ b,
    u16* __restrict__ oh, u16* __restrict__ ol)
{
  int i = blockIdx.x*256 + threadIdx.x;
  if (i >= 6352*512) return;
  splitstore(a[i] + b[i], oh+i, ol+i);
}

// ---------- split-bf16 GEMM: C[M,N] = A[M,K(hi/lo)] @ Bt[N,K(hi/lo)] + bias ----------
// AMODE 0: direct A[m][k].  AMODE 1: conv gather CW=80.  AMODE 2: conv gather CW=512.
// EPI 0: f32 out. EPI 1: relu -> split out. EPI 2: clip(0,20) -> split out.
template<int AMODE, int EPI>
__global__ __launch_bounds__(256,1)
void gemm_split(const u16* __restrict__ Ah, const u16* __restrict__ Al,
                const u16* __restrict__ Bh, const u16* __restrict__ Bl,
                const float* __restrict__ bias,
                float* __restrict__ outF, u16* __restrict__ outH, u16* __restrict__ outL,
                int M, int N, int K, int Kvalid, int TIN, int TOUT)
{
  constexpr int CW = (AMODE==1) ? 80 : 512;
  const int tid  = threadIdx.x;
  const int lane = tid & 63;
  const int w    = tid >> 6;
  const int wm = w >> 1, wn = w & 1;
  const int r  = lane & 15, kg = lane >> 4;
  const int m0 = blockIdx.y * 64 + wm * 32;
  const int n0 = blockIdx.x * 64 + wn * 32;

  long abase[2];
  #pragma unroll
  for (int mt = 0; mt < 2; ++mt){
    int m = m0 + mt*16 + r;
    int mc = m < M ? m : M - 1;
    if (AMODE == 0) abase[mt] = (long)mc * K;
    else { int bb = mc / TOUT; int tt = mc - bb * TOUT; abase[mt] = ((long)bb * TIN + 2*tt) * CW; }
  }
  long bbase[2];
  #pragma unroll
  for (int nt = 0; nt < 2; ++nt){
    int n = n0 + nt*16 + r;
    int nc = n < N ? n : N - 1;
    bbase[nt] = (long)nc * K;
  }

  f32x4 acc[2][2];
  #pragma unroll
  for (int a_ = 0; a_ < 2; ++a_)
    #pragma unroll
    for (int b_ = 0; b_ < 2; ++b_) acc[a_][b_] = f32x4{0.f,0.f,0.f,0.f};

  const bf16x8 zfrag = {0,0,0,0,0,0,0,0};
  const int koff = kg * 8;
  const int KT = K >> 5;
  for (int kt = 0; kt < KT; ++kt){
    int kf = kt*32 + koff;
    bf16x8 ah[2], al[2], bh[2], bl[2];
    #pragma unroll
    for (int nt = 0; nt < 2; ++nt){
      bh[nt] = *(const bf16x8*)(Bh + bbase[nt] + kf);
      bl[nt] = *(const bf16x8*)(Bl + bbase[nt] + kf);
    }
    #pragma unroll
    for (int mt = 0; mt < 2; ++mt){
      if (AMODE == 0){
        long ao = abase[mt] + kf;
        ah[mt] = *(const bf16x8*)(Ah + ao); al[mt] = *(const bf16x8*)(Al + ao);
      } else {
        if (kf < Kvalid){
          int kw = kf / CW; int ci = kf - kw*CW;
          long ao = abase[mt] + (long)kw*CW + ci;
          ah[mt] = *(const bf16x8*)(Ah + ao); al[mt] = *(const bf16x8*)(Al + ao);
        } else { ah[mt] = zfrag; al[mt] = zfrag; }
      }
    }
    #pragma unroll
    for (int mt = 0; mt < 2; ++mt)
      #pragma unroll
      for (int nt = 0; nt < 2; ++nt){
        acc[mt][nt] = MFMA(ah[mt], bh[nt], acc[mt][nt]);
        acc[mt][nt] = MFMA(ah[mt], bl[nt], acc[mt][nt]);
        acc[mt][nt] = MFMA(al[mt], bh[nt], acc[mt][nt]);
      }
  }

  #pragma unroll
  for (int nt = 0; nt < 2; ++nt){
    int n = n0 + nt*16 + r;
    if (n >= N) continue;
    float bv = bias ? bias[n] : 0.f;
    #pragma unroll
    for (int mt = 0; mt < 2; ++mt){
      #pragma unroll
      for (int q = 0; q < 4; ++q){
        int m = m0 + mt*16 + kg*4 + q;
        if (m >= M) continue;
        float v = acc[mt][nt][q] + bv;
        if (EPI == 1) v = fmaxf(v, 0.f);
        if (EPI == 2) v = fminf(fmaxf(v, 0.f), 20.f);
        long o = (long)m * N + n;
        if (EPI == 0) outF[o] = v;
        else { u16 h = f2bf(v); outH[o] = h; outL[o] = f2bf(v - bf2f(h)); }
      }
    }
  }
}

// ---------- persistent bidirectional GRU layer ----------
// 64 blocks: dir = bx>>5, slice s = bx&31 (16 h-cols each). Wh fragments pinned in VGPRs
// (keep-alive asm INSIDE the t-loop: the R4 pre-loop pin was defeated by regalloc ->
// VGPR_Count=88 < 96 needed -> per-step scratch reload on the MFMA critical path).
// Per-step sync: per-block monotonic flag, consumers poll 32 flags with 32 lanes.
// h exchange via sc0/sc1 coherent-point accesses — no cache invalidation, no RMW.
__global__ __launch_bounds__(256,1)
void gru_layer(const float* __restrict__ xp,     // [2][6352][1536]
               const u16* __restrict__ WhH, const u16* __restrict__ WhL, // [2][1536][512]
               const float* __restrict__ hbias,  // [2][1536]
               float* __restrict__ yf, float* __restrict__ yb, // [6352][512] each
               u16* __restrict__ hbH_, u16* __restrict__ hbL_, // [2][2][16][512] each plane
               u32* __restrict__ flags)          // [2][32] steps-completed per block
{
  const int dir = blockIdx.x >> 5;
  const int s   = blockIdx.x & 31;
  const int tid = threadIdx.x, lane = tid & 63, w = tid >> 6;
  const int r = lane & 15, kg = lane >> 4;

  const float* xpd = xp + (long)dir * (6352L*1536);
  const u16* whh = WhH + (long)dir * (1536L*512);
  const u16* whl = WhL + (long)dir * (1536L*512);
  const float* hb = hbias + dir * 1536;
  float* y = dir ? yb : yf;
  u16* hbH = hbH_ + dir * (2*8192);
  u16* hbL = hbL_ + dir * (2*8192);
  u32* flg = flags + dir * 32;

  __shared__ float red[4][3][64][4];

  // persistent Wh fragments: wave w covers ktiles 4w..4w+3; gates g=0..2
  bf16x8 Bh[3][4], Bl[3][4];
  #pragma unroll
  for (int g = 0; g < 3; ++g){
    long nb = (long)(g*512 + s*16 + r) * 512;
    #pragma unroll
    for (int kk = 0; kk < 4; ++kk){
      int k = (w*4 + kk)*32 + kg*8;
      Bh[g][kk] = *(const bf16x8*)(whh + nb + k);
      Bl[g][kk] = *(const bf16x8*)(whl + nb + k);
    }
  }

  const int gb = tid >> 4, gj = tid & 15;
  const int gcol = s*16 + gj;
  const float bz = hb[gcol], br = hb[512 + gcol], bhh = hb[1024 + gcol];
  const int rl = ((gb >> 2) << 4) | gj;  // lane holding our (row=gb,col=gj)
  const int rq = gb & 3;
  const int rb = r * 512 + kg * 8;
  float hreg = 0.f;

  for (int t = 0; t < 397; ++t){
    // keep-alive: force all 24 Wh fragments resident in VGPRs at every iteration
    #pragma unroll
    for (int g = 0; g < 3; ++g)
      #pragma unroll
      for (int kk = 0; kk < 4; ++kk)
        asm volatile("" : "+v"(Bh[g][kk]), "+v"(Bl[g][kk]));

    const int tpos = dir ? (396 - t) : t;
    const long xb_ = ((long)gb*397 + tpos)*1536 + gcol;
    float xz = xpd[xb_], xr = xpd[xb_ + 512], xh = xpd[xb_ + 1024];

    f32x4 a0 = f32x4{0.f,0.f,0.f,0.f}, a1 = a0, a2 = a0;
    if (t > 0){
      if (w == 0){
        const u32 tgt = (u32)t;
        for (;;){
          int done = 1;
          if (lane < 32)
            done = (__hip_atomic_load(flg + lane, __ATOMIC_RELAXED,
                                      __HIP_MEMORY_SCOPE_AGENT) >= tgt);
          if (__all(done)) break;
        }
      }
      __syncthreads();
      const u16* hH = hbH + (t & 1) * 8192;
      const u16* hL = hbL + (t & 1) * 8192;
      bf16x8 ah[4], al[4];
      #pragma unroll
      for (int kk = 0; kk < 4; ++kk){
        int k = (w*4 + kk) * 32;
        ah[kk] = ld128_sys(hH + rb + k);
        al[kk] = ld128_sys(hL + rb + k);
      }
      asm volatile("s_waitcnt vmcnt(0)" ::: "memory");
      __builtin_amdgcn_sched_barrier(0);
      #pragma unroll
      for (int kk = 0; kk < 4; ++kk){
        a0 = MFMA(ah[kk], Bh[0][kk], a0); a0 = MFMA(ah[kk], Bl[0][kk], a0); a0 = MFMA(al[kk], Bh[0][kk], a0);
        a1 = MFMA(ah[kk], Bh[1][kk], a1); a1 = MFMA(ah[kk], Bl[1][kk], a1); a1 = MFMA(al[kk], Bh[1][kk], a1);
        a2 = MFMA(ah[kk], Bh[2][kk], a2); a2 = MFMA(ah[kk], Bl[2][kk], a2); a2 = MFMA(al[kk], Bh[2][kk], a2);
      }
    }
    *(f32x4*)&red[w][0][lane][0] = a0;
    *(f32x4*)&red[w][1][lane][0] = a1;
    *(f32x4*)&red[w][2][lane][0] = a2;
    __syncthreads();
    float rz = bz, rr = br, rh = bhh;
    #pragma unroll
    for (int ww = 0; ww < 4; ++ww){
      rz += red[ww][0][rl][rq];
      rr += red[ww][1][rl][rq];
      rh += red[ww][2][rl][rq];
    }
    float z  = 1.f / (1.f + __expf(-(xz + rz)));
    float rg = 1.f / (1.f + __expf(-(xr + rr)));
    float hh = fmaxf(xh + rg * rh, 0.f);
    hreg = z * hreg + (1.f - z) * hh;

    // release: coherent h stores -> drain -> block barrier -> flag post
    {
      u16* oH = hbH + ((t+1) & 1) * 8192;
      u16* oL = hbL + ((t+1) & 1) * 8192;
      u16 hhi = f2bf(hreg);
      u16 hlo = f2bf(hreg - bf2f(hhi));
      st16_sys(oH + gb*512 + gcol, hhi);
      st16_sys(oL + gb*512 + gcol, hlo);
    }
    asm volatile("s_waitcnt vmcnt(0)" ::: "memory");
    __syncthreads();
    if (tid == 0)
      __hip_atomic_store(flg + s, (u32)(t + 1), __ATOMIC_RELAXED,
                         __HIP_MEMORY_SCOPE_AGENT);
    y[((long)gb*397 + tpos)*512 + gcol] = hreg;  // off critical path
  }
}

// ---------- in-place row softmax on d_out [6352][6000] ----------
__global__ __launch_bounds__(256,1) void k_softmax(float* __restrict__ out)
{
  const int tid = threadIdx.x;
  float* prow = out + (long)blockIdx.x * 6000;
  float vals[24];
  float mx = -3.0e38f;
  #pragma unroll
  for (int i = 0; i < 24; ++i){
    int idx = tid + i*256;
    vals[i] = (idx < 6000) ? prow[idx] : -3.0e38f;
    mx = fmaxf(mx, vals[i]);
  }
  #pragma unroll
  for (int o = 32; o; o >>= 1) mx = fmaxf(mx, __shfl_xor(mx, o));
  __shared__ float sred[4];
  if ((tid & 63) == 0) sred[tid >> 6] = mx;
  __syncthreads();
  mx = fmaxf(fmaxf(sred[0], sred[1]), fmaxf(sred[2], sred[3]));
  __syncthreads();
  float sum = 0.f;
  #pragma unroll
  for (int i = 0; i < 24; ++i){
    int idx = tid + i*256;
    vals[i] = (idx < 6000) ? expf(vals[i] - mx) : 0.f;
    sum += vals[i];
  }
  #pragma unroll
  for (int o = 32; o; o >>= 1) sum += __shfl_xor(sum, o);
  if ((tid & 63) == 0) sred[tid >> 6] = sum;
  __syncthreads();
  sum = sred[0] + sred[1] + sred[2] + sred[3];
  float inv = 1.f / sum;
  #pragma unroll
  for (int i = 0; i < 24; ++i){
    int idx = tid + i*256;
    if (idx < 6000) prow[idx] = vals[i] * inv;
  }
}

// ---------- host ----------
extern "C" void kernel_launch(void* const* d_in, const int* in_sizes, int n_in,
                              void* d_out, int out_size, void* d_ws, size_t ws_size,
                              hipStream_t stream)
{
  (void)in_sizes; (void)n_in; (void)out_size; (void)ws_size;
  const float* x    = (const float*)d_in[0];
  const float* bn1g = (const float*)d_in[1];
  const float* bn1b = (const float*)d_in[2];
  const float* bn1m = (const float*)d_in[3];
  const float* bn1v = (const float*)d_in[4];
  const float* cw0  = (const float*)d_in[5];
  const float* cb0  = (const float*)d_in[6];
  const float* cw1  = (const float*)d_in[7];
  const float* cb1  = (const float*)d_in[8];
  const float* bn2g = (const float*)d_in[9];
  const float* bn2b = (const float*)d_in[10];
  const float* bn2m = (const float*)d_in[11];
  const float* bn2v = (const float*)d_in[12];
  const float* gwx  = (const float*)d_in[13];
  const float* gwh  = (const float*)d_in[14];
  const float* gbia = (const float*)d_in[15];
  const float* bn3g = (const float*)d_in[16];
  const float* bn3b = (const float*)d_in[17];
  const float* bn3m = (const float*)d_in[18];
  const float* bn3v = (const float*)d_in[19];
  const float* fcw  = (const float*)d_in[20];
  const float* fcb  = (const float*)d_in[21];
  const float* smw  = (const float*)d_in[22];
  const float* smb  = (const float*)d_in[23];

  char* p = (char*)d_ws;
  auto alloc = [&](size_t bytes)->char*{
    char* q = p; p += (bytes + 255) & ~(size_t)255; return q;
  };
  const size_t NX=2048000, NC1W=512*416, NC1O=12768L*512, NC2W=512*2560,
               NC2O=6352L*512, NWX=6L*1536*512, NXP=2L*6352*1536,
               NSMW=6000L*512, NFCW=512*512, NHB=2L*2*8192;

  u16 *xbnH=(u16*)alloc(NX*2),  *xbnL=(u16*)alloc(NX*2);
  u16 *c1wH=(u16*)alloc(NC1W*2),*c1wL=(u16*)alloc(NC1W*2);
  u16 *c1oH=(u16*)alloc(NC1O*2),*c1oL=(u16*)alloc(NC1O*2);
  u16 *c2wH=(u16*)alloc(NC2W*2),*c2wL=(u16*)alloc(NC2W*2);
  u16 *c2oH=(u16*)alloc(NC2O*2),*c2oL=(u16*)alloc(NC2O*2);
  u16 *wxH=(u16*)alloc(NWX*2),  *wxL=(u16*)alloc(NWX*2);
  u16 *whH=(u16*)alloc(NWX*2),  *whL=(u16*)alloc(NWX*2);
  float *xbias=(float*)alloc(6*1536*4), *hbias=(float*)alloc(6*1536*4);
  float *xp=(float*)alloc(NXP*4);
  float *yf=(float*)alloc(NC2O*4), *yb=(float*)alloc(NC2O*4);
  u16 *ysH=(u16*)alloc(NC2O*2), *ysL=(u16*)alloc(NC2O*2);
  u16 *fcwH=(u16*)alloc(NFCW*2),*fcwL=(u16*)alloc(NFCW*2);
  float *fcb2=(float*)alloc(512*4);
  u16 *fcoH=(u16*)alloc(NC2O*2),*fcoL=(u16*)alloc(NC2O*2);
  u16 *smwH=(u16*)alloc(NSMW*2),*smwL=(u16*)alloc(NSMW*2);
  u16 *hbH=(u16*)alloc(NHB*2),  *hbL=(u16*)alloc(NHB*2);
  u32 *flags=(u32*)alloc(3*64*4);   // [layer][dir][32]

  hipMemsetAsync(flags, 0, 3*64*4, stream);

  k_bn1_split<<<8000,256,0,stream>>>(x, bn1g,bn1b,bn1m,bn1v, xbnH,xbnL);
  k_prep_c1w <<<832,256,0,stream>>>(cw0, c1wH,c1wL);
  k_prep_c2w <<<5120,256,0,stream>>>(cw1, c2wH,c2wL);
  k_prep_wx  <<<18432,256,0,stream>>>(gwx, bn2g,bn2v, wxH,wxL);
  k_prep_wh  <<<18432,256,0,stream>>>(gwh, whH,whL);
  k_prep_grub<<<36,256,0,stream>>>(gbia, gwx, bn2g,bn2b,bn2m,bn2v, xbias,hbias);
  k_prep_fcw <<<1024,256,0,stream>>>(fcw, bn3g,bn3v, fcwH,fcwL);
  k_prep_fcb <<<2,256,0,stream>>>(fcw,fcb, bn3g,bn3b,bn3m,bn3v, fcb2);
  k_prep_smw <<<12000,256,0,stream>>>(smw, smwH,smwL);

  // conv1: M=12768, N=512, K=416 (valid 400), stride2 gather from xbn [16*1600][80]
  gemm_split<1,1><<<dim3(8,200),256,0,stream>>>(xbnH,xbnL, c1wH,c1wL, cb0,
      nullptr, c1oH,c1oL, 12768,512,416, 400, 1600,798);
  // conv2: M=6352, N=512, K=2560, gather from c1o [12768][512]
  gemm_split<2,1><<<dim3(8,100),256,0,stream>>>(c1oH,c1oL, c2wH,c2wL, cb1,
      nullptr, c2oH,c2oL, 6352,512,2560, 2560, 798,397);

  const u16 *aH = c2oH, *aL = c2oL;
  for (int l = 0; l < 3; ++l){
    for (int d = 0; d < 2; ++d){
      gemm_split<0,0><<<dim3(24,100),256,0,stream>>>(aH,aL,
          wxH + (size_t)(l*2+d)*786432, wxL + (size_t)(l*2+d)*786432,
          xbias + (l*2+d)*1536,
          xp + (size_t)d*9756672, nullptr,nullptr,
          6352,1536,512, 512, 0,0);
    }
    gru_layer<<<64,256,0,stream>>>(xp,
        whH + (size_t)l*2*786432, whL + (size_t)l*2*786432,
        hbias + l*2*1536, yf,yb, hbH,hbL, flags + l*64);
    k_sumsplit<<<12704,256,0,stream>>>(yf,yb, ysH,ysL);
    aH = ysH; aL = ysL;
  }

  // fc: clip(relu(x@W+b),20) -> split
  gemm_split<0,2><<<dim3(8,100),256,0,stream>>>(ysH,ysL, fcwH,fcwL, fcb2,
      nullptr, fcoH,fcoL, 6352,512,512, 512, 0,0);
  // logits -> d_out (f32), then in-place softmax
  gemm_split<0,0><<<dim3(94,100),256,0,stream>>>(fcoH,fcoL, smwH,smwL, smb,
      (float*)d_out, nullptr,nullptr, 6352,6000,512, 512, 0,0);
  k_softmax<<<6352,256,0,stream>>>((float*)d_out);
}